// Round 6
// baseline (742.885 us; speedup 1.0000x reference)
//
#include <hip/hip_runtime.h>
#include <math.h>

#define N_NODES 20000
#define N_EDGES 200000
#define NDIM 128
#define EDIM 64
#define HDIM 256
#define HEADS 4
#define NH 1024
#define NLAYERS 3

typedef __attribute__((ext_vector_type(8))) short short8;
typedef __attribute__((ext_vector_type(4))) float floatx4;

__device__ __forceinline__ float b2f(unsigned short u) {
    union { unsigned u; float f; } c; c.u = ((unsigned)u) << 16; return c.f;
}
__device__ __forceinline__ float b2f_lo(unsigned u) {
    union { unsigned u; float f; } c; c.u = u << 16; return c.f;
}
__device__ __forceinline__ float b2f_hi(unsigned u) {
    union { unsigned u; float f; } c; c.u = u & 0xffff0000u; return c.f;
}
__device__ __forceinline__ unsigned short f2b(float f) {
    union { float f; unsigned u; } c; c.f = f;
    unsigned u = c.u;
    return (unsigned short)((u + 0x7FFFu + ((u >> 16) & 1u)) >> 16);
}

__device__ __forceinline__ float wave_reduce_sum(float v) {
    #pragma unroll
    for (int off = 32; off > 0; off >>= 1) v += __shfl_down(v, off, 64);
    return v;
}

// ---------------- CSR build ----------------
__global__ void hist_kernel(const int* __restrict__ dst0, int* __restrict__ cnt) {
    int e = blockIdx.x * 256 + threadIdx.x;
    if (e < N_EDGES) atomicAdd(&cnt[dst0[e]], 1);
}

__global__ void scan_kernel(const int* __restrict__ cnt, int* __restrict__ row_ptr) {
    __shared__ int wsum[4];
    __shared__ int carry_sh;
    int tid = threadIdx.x, lane = tid & 63, wid = tid >> 6;
    if (tid == 0) carry_sh = 0;
    __syncthreads();
    for (int base = 0; base < N_NODES; base += 256) {
        int v = (base + tid < N_NODES) ? cnt[base + tid] : 0;
        int s = v;
        #pragma unroll
        for (int off = 1; off < 64; off <<= 1) {
            int t = __shfl_up(s, off, 64);
            if (lane >= off) s += t;
        }
        if (lane == 63) wsum[wid] = s;
        int carry = carry_sh;
        __syncthreads();
        int woff = 0;
        for (int w = 0; w < wid; w++) woff += wsum[w];
        int incl = s + woff;
        if (base + tid < N_NODES) row_ptr[base + tid] = carry + incl - v;
        __syncthreads();
        if (tid == 255) carry_sh = carry + incl;
        __syncthreads();
    }
    if (tid == 0) row_ptr[N_NODES] = carry_sh;
}

__global__ void fill_kernel(const int* __restrict__ dst0, const int* __restrict__ row_ptr,
                            int* __restrict__ fillc, int* __restrict__ edge_ids) {
    int e = blockIdx.x * 256 + threadIdx.x;
    if (e < N_EDGES) {
        int d = dst0[e];
        int p = atomicAdd(&fillc[d], 1);
        edge_ids[row_ptr[d] + p] = e;
    }
}

// ---------------- weight prep ----------------
__global__ void transpose_bf(const float* __restrict__ in, unsigned short* __restrict__ out,
                             int K, int Nn, size_t in_bs, size_t out_bs) {
    in += blockIdx.z * in_bs;
    out += blockIdx.z * out_bs;
    __shared__ float sh[32][33];
    int tx = threadIdx.x, ty = threadIdx.y;
    int kb = blockIdx.y * 32, nb = blockIdx.x * 32;
    #pragma unroll
    for (int i = 0; i < 32; i += 8)
        sh[ty + i][tx] = in[(size_t)(kb + ty + i) * Nn + nb + tx];
    __syncthreads();
    #pragma unroll
    for (int i = 0; i < 32; i += 8)
        out[(size_t)(nb + ty + i) * K + kb + tx] = f2b(sh[tx][ty + i]);
}

// gw2t[l][d][h*256+k] = gat_w[l][k][h*256+d] * 0.25 (head-mean folded in)
__global__ void gat_w_prep(const float* __restrict__ in, unsigned short* __restrict__ out) {
    int z = blockIdx.z, l = z >> 2, h = z & 3;
    __shared__ float sh[32][33];
    int tx = threadIdx.x, ty = threadIdx.y;
    int kb = blockIdx.y * 32, db = blockIdx.x * 32;
    const float* src = in + (size_t)l * HDIM * NH + (size_t)h * HDIM;
    unsigned short* dst = out + (size_t)l * HDIM * NH + (size_t)h * HDIM;
    #pragma unroll
    for (int i = 0; i < 32; i += 8)
        sh[ty + i][tx] = src[(size_t)(kb + ty + i) * NH + db + tx];
    __syncthreads();
    #pragma unroll
    for (int i = 0; i < 32; i += 8)
        dst[(size_t)(db + ty + i) * NH + kb + tx] = f2b(0.25f * sh[tx][ty + i]);
}

// ws_s[l*4+h][k] = sum_d gat_w[l][k][h*256+d] * att_src[l][h][d]; same for dst
__global__ void ws_prep(const float* __restrict__ gat_w, const float* __restrict__ att_src,
                        const float* __restrict__ att_dst,
                        float* __restrict__ ws_s, float* __restrict__ ws_d) {
    int l = blockIdx.x >> 2, h = blockIdx.x & 3;
    int k = threadIdx.x;
    const float* wrow = gat_w + (size_t)l * HDIM * NH + (size_t)k * NH + h * HDIM;
    const float* as = att_src + (size_t)l * NH + h * HDIM;
    const float* ad = att_dst + (size_t)l * NH + h * HDIM;
    float s1 = 0.f, s2 = 0.f;
    for (int d = 0; d < HDIM; d += 4) {
        float4 w4 = *(const float4*)(wrow + d);
        float4 a4 = *(const float4*)(as + d);
        float4 b4 = *(const float4*)(ad + d);
        s1 += w4.x * a4.x + w4.y * a4.y + w4.z * a4.z + w4.w * a4.w;
        s2 += w4.x * b4.x + w4.y * b4.y + w4.z * b4.z + w4.w * b4.w;
    }
    ws_s[(size_t)blockIdx.x * HDIM + k] = s1;
    ws_d[(size_t)blockIdx.x * HDIM + k] = s2;
}

__global__ void conv_bf(const float* __restrict__ in, unsigned short* __restrict__ out) {
    int i = blockIdx.x * 256 + threadIdx.x;
    float4 v = ((const float4*)in)[i];
    ushort4 o;
    o.x = f2b(v.x); o.y = f2b(v.y); o.z = f2b(v.z); o.w = f2b(v.w);
    ((ushort4*)out)[i] = o;
}

// ---------------- bf16 MFMA GEMM ----------------
template <bool RELU, bool BIAS>
__global__ __launch_bounds__(256) void gemm_bf16(
    const unsigned short* __restrict__ A, const unsigned short* __restrict__ Bt,
    const float* __restrict__ bias, unsigned short* __restrict__ C,
    int M, int Ntot, int K)
{
    __shared__ char lds[32768];
    unsigned short* As = (unsigned short*)lds;
    unsigned short* Bs = (unsigned short*)(lds + 8192);
    unsigned short* Cs = (unsigned short*)lds;

    int tid = threadIdx.x;
    int lane = tid & 63;
    int wid = tid >> 6;
    int row0 = blockIdx.y * 128;
    int col0 = blockIdx.x * 128;
    int wm = (wid >> 1) * 64;
    int wn = (wid & 1) * 64;
    int lm = lane & 15;
    int q8 = (lane >> 4) * 8;
    int q4 = (lane >> 4) * 4;

    floatx4 acc[4][4];
    #pragma unroll
    for (int i = 0; i < 4; i++)
        #pragma unroll
        for (int j = 0; j < 4; j++)
            acc[i][j] = (floatx4)(0.f);

    for (int k0 = 0; k0 < K; k0 += 32) {
        #pragma unroll
        for (int r = 0; r < 2; r++) {
            int chunk = tid + r * 256;
            int arow = chunk >> 2;
            int acol = (chunk & 3) * 8;
            int garow = row0 + arow; if (garow > M - 1) garow = M - 1;
            __builtin_amdgcn_global_load_lds(
                (__attribute__((address_space(1))) const void*)(A + (size_t)garow * K + k0 + acol),
                (__attribute__((address_space(3))) void*)(As + chunk * 8), 16, 0, 0);
            __builtin_amdgcn_global_load_lds(
                (__attribute__((address_space(1))) const void*)(Bt + (size_t)(col0 + arow) * K + k0 + acol),
                (__attribute__((address_space(3))) void*)(Bs + chunk * 8), 16, 0, 0);
        }
        __syncthreads();
        short8 af[4], bf[4];
        #pragma unroll
        for (int i = 0; i < 4; i++)
            af[i] = *(const short8*)(As + (wm + i * 16 + lm) * 32 + q8);
        #pragma unroll
        for (int j = 0; j < 4; j++)
            bf[j] = *(const short8*)(Bs + (wn + j * 16 + lm) * 32 + q8);
        #pragma unroll
        for (int i = 0; i < 4; i++)
            #pragma unroll
            for (int j = 0; j < 4; j++)
                acc[i][j] = __builtin_amdgcn_mfma_f32_16x16x32_bf16(af[i], bf[j], acc[i][j], 0, 0, 0);
        __syncthreads();
    }

    #pragma unroll
    for (int i = 0; i < 4; i++) {
        #pragma unroll
        for (int j = 0; j < 4; j++) {
            int cl = wn + j * 16 + lm;
            float bv = BIAS ? bias[col0 + cl] : 0.f;
            #pragma unroll
            for (int reg = 0; reg < 4; reg++) {
                int rl = wm + i * 16 + q4 + reg;
                float v = acc[i][j][reg];
                if (BIAS) v += bv;
                if (RELU) v = fmaxf(v, 0.f);
                Cs[rl * 128 + cl] = f2b(v);
            }
        }
    }
    __syncthreads();
    int row = tid >> 1;
    int ce = (tid & 1) * 64;
    if (row0 + row < M) {
        #pragma unroll
        for (int u = 0; u < 8; u++) {
            int4 v = *(const int4*)(Cs + row * 128 + ce + u * 8);
            *(int4*)(C + (size_t)(row0 + row) * Ntot + col0 + ce + u * 8) = v;
        }
    }
}

// ---------------- per-layer small precompute ----------------
__global__ void layer_prep3(const float* __restrict__ edge_enc_w, const float* __restrict__ edge_enc_b,
                            const float* __restrict__ lin_edge_w, const float* __restrict__ att_edge,
                            float* __restrict__ wmean3, float* __restrict__ scal3)
{
    int l = blockIdx.x;
    const float* eew = edge_enc_w + (size_t)l * EDIM * HDIM;
    const float* eeb = edge_enc_b + (size_t)l * HDIM;
    const float* lew = lin_edge_w + (size_t)l * NH;
    const float* ae  = att_edge + (size_t)l * NH;
    float* wm = wmean3 + l * 64;
    float* sc = scal3 + l * 8;
    int tid = threadIdx.x;
    if (tid < 64) {
        float s = 0.f;
        for (int d = 0; d < HDIM; d++) s += eew[tid * HDIM + d];
        wm[tid] = s * (1.f / HDIM);
    } else if (tid < 68) {
        int h = tid - 64;
        float s = 0.f;
        for (int d = 0; d < HDIM; d++) s += lew[h * HDIM + d] * ae[h * HDIM + d];
        sc[h] = s;
    } else if (tid == 68) {
        float s = 0.f;
        for (int d = 0; d < HDIM; d++) s += eeb[d];
        sc[4] = s * (1.f / HDIM);
    }
}

__global__ __launch_bounds__(256) void edge_weights_all(const float* __restrict__ edge_attr,
                                                        const float* __restrict__ wmean3,
                                                        const float* __restrict__ scal3,
                                                        float* __restrict__ ew3)
{
    int e = blockIdx.x * 4 + (threadIdx.x >> 6);
    int lane = threadIdx.x & 63;
    float a = edge_attr[(size_t)e * EDIM + lane];
    float v0 = a * wmean3[lane];
    float v1 = a * wmean3[64 + lane];
    float v2 = a * wmean3[128 + lane];
    #pragma unroll
    for (int off = 32; off > 0; off >>= 1) {
        v0 += __shfl_down(v0, off, 64);
        v1 += __shfl_down(v1, off, 64);
        v2 += __shfl_down(v2, off, 64);
    }
    if (lane == 0) {
        ew3[e] = v0 + scal3[4];
        ew3[N_EDGES + e] = v1 + scal3[12];
        ew3[2 * N_EDGES + e] = v2 + scal3[20];
    }
}

__global__ void loop_weights_all(const float* __restrict__ ew3, const int* __restrict__ row_ptr,
                                 const int* __restrict__ edge_ids, float* __restrict__ loopw3)
{
    int n = blockIdx.x * 256 + threadIdx.x;
    if (n >= N_NODES) return;
    int r0 = row_ptr[n], r1 = row_ptr[n + 1];
    float s0 = 0.f, s1 = 0.f, s2 = 0.f;
    for (int i = r0; i < r1; i++) {
        int e = edge_ids[i];
        s0 += ew3[e]; s1 += ew3[N_EDGES + e]; s2 += ew3[2 * N_EDGES + e];
    }
    float inv = 1.f / fmaxf((float)(r1 - r0), 1.f);
    loopw3[n] = s0 * inv;
    loopw3[N_NODES + n] = s1 * inv;
    loopw3[2 * N_NODES + n] = s2 * inv;
}

// a_s/a_d from x (xp never materialized): a_s[n,h] = x[n]·ws_s[h]
__global__ __launch_bounds__(256) void attn_x(const unsigned short* __restrict__ x_bf,
                                              const float* __restrict__ ws_s,
                                              const float* __restrict__ ws_d,
                                              float* __restrict__ a_s,
                                              float* __restrict__ a_d)
{
    int n = blockIdx.x;
    int h = threadIdx.x >> 6;
    int lane = threadIdx.x & 63;
    ushort4 xv = *(const ushort4*)(x_bf + (size_t)n * HDIM + lane * 4);
    float4 s4 = *(const float4*)(ws_s + h * HDIM + lane * 4);
    float4 d4 = *(const float4*)(ws_d + h * HDIM + lane * 4);
    float x0 = b2f(xv.x), x1 = b2f(xv.y), x2 = b2f(xv.z), x3 = b2f(xv.w);
    float ss = x0 * s4.x + x1 * s4.y + x2 * s4.z + x3 * s4.w;
    float sd = x0 * d4.x + x1 * d4.y + x2 * d4.z + x3 * d4.w;
    ss = wave_reduce_sum(ss);
    sd = wave_reduce_sum(sd);
    if (lane == 0) { a_s[n * 4 + h] = ss; a_d[n * 4 + h] = sd; }
}

// Segment softmax + aggregate x (512B rows, 10MB working set) into agg[N][h*256+k].
// Each wave covers all 256 dims (lane*4) for all 4 heads; waves split edges.
__global__ __launch_bounds__(256) void gat_aggregate_x(
    const unsigned short* __restrict__ x_bf, const float* __restrict__ a_s,
    const float* __restrict__ a_d, const float* __restrict__ ew,
    const float* __restrict__ loopw, const float* __restrict__ scal,
    const int* __restrict__ row_ptr, const int* __restrict__ edge_ids,
    const int* __restrict__ src0, unsigned short* __restrict__ agg)
{
    int n = blockIdx.x;
    int tid = threadIdx.x, lane = tid & 63, wid = tid >> 6;
    int r0 = row_ptr[n];
    int deg = row_ptr[n + 1] - r0;
    int cnt = deg + 1;

    __shared__ float c_sh[4], ad_sh[4];
    __shared__ float wred[4][4];
    __shared__ float alphaT[256][4];
    __shared__ int src_ch[256];
    __shared__ float acc_sh[4][1024];

    if (tid < 4) { c_sh[tid] = scal[tid]; ad_sh[tid] = a_d[n * 4 + tid]; }
    __syncthreads();

    // pass A: per-head max
    float m4[4] = {-1e30f, -1e30f, -1e30f, -1e30f};
    for (int idx = tid; idx < cnt; idx += 256) {
        int sn; float w;
        if (idx < deg) { int e = edge_ids[r0 + idx]; sn = src0[e]; w = ew[e]; }
        else           { sn = n; w = loopw[n]; }
        float4 as4 = *(const float4*)(a_s + sn * 4);
        float zz[4] = {as4.x, as4.y, as4.z, as4.w};
        #pragma unroll
        for (int h = 0; h < 4; h++) {
            float z = zz[h] + ad_sh[h] + c_sh[h] * w;
            z = z > 0.f ? z : 0.2f * z;
            m4[h] = fmaxf(m4[h], z);
        }
    }
    #pragma unroll
    for (int off = 32; off > 0; off >>= 1)
        #pragma unroll
        for (int h = 0; h < 4; h++)
            m4[h] = fmaxf(m4[h], __shfl_down(m4[h], off, 64));
    if (lane == 0)
        #pragma unroll
        for (int h = 0; h < 4; h++) wred[wid][h] = m4[h];
    __syncthreads();
    float mh[4];
    #pragma unroll
    for (int h = 0; h < 4; h++)
        mh[h] = fmaxf(fmaxf(wred[0][h], wred[1][h]), fmaxf(wred[2][h], wred[3][h]));

    // pass B: per-head sum of exp
    float s4[4] = {0.f, 0.f, 0.f, 0.f};
    for (int idx = tid; idx < cnt; idx += 256) {
        int sn; float w;
        if (idx < deg) { int e = edge_ids[r0 + idx]; sn = src0[e]; w = ew[e]; }
        else           { sn = n; w = loopw[n]; }
        float4 as4 = *(const float4*)(a_s + sn * 4);
        float zz[4] = {as4.x, as4.y, as4.z, as4.w};
        #pragma unroll
        for (int h = 0; h < 4; h++) {
            float z = zz[h] + ad_sh[h] + c_sh[h] * w;
            z = z > 0.f ? z : 0.2f * z;
            s4[h] += __expf(z - mh[h]);
        }
    }
    #pragma unroll
    for (int off = 32; off > 0; off >>= 1)
        #pragma unroll
        for (int h = 0; h < 4; h++)
            s4[h] += __shfl_down(s4[h], off, 64);
    __syncthreads();
    if (lane == 0)
        #pragma unroll
        for (int h = 0; h < 4; h++) wred[wid][h] = s4[h];
    __syncthreads();
    float inv_s[4];
    #pragma unroll
    for (int h = 0; h < 4; h++)
        inv_s[h] = 1.f / (wred[0][h] + wred[1][h] + wred[2][h] + wred[3][h]);

    // aggregation: acc[head][4 dims] per thread; waves split edges (pairs, stride 8)
    float acc[4][4] = {};
    for (int base = 0; base < cnt; base += 256) {
        int mcnt = min(256, cnt - base);
        int mpad = (mcnt + 7) & ~7;
        for (int t = tid; t < mpad; t += 256) {
            if (t < mcnt) {
                int idx = base + t; int sn; float w;
                if (idx < deg) { int e = edge_ids[r0 + idx]; sn = src0[e]; w = ew[e]; }
                else           { sn = n; w = loopw[n]; }
                src_ch[t] = sn;
                float4 as4 = *(const float4*)(a_s + sn * 4);
                float zz[4] = {as4.x, as4.y, as4.z, as4.w};
                float4 al;
                float* alp = (float*)&al;
                #pragma unroll
                for (int h = 0; h < 4; h++) {
                    float z = zz[h] + ad_sh[h] + c_sh[h] * w;
                    z = z > 0.f ? z : 0.2f * z;
                    alp[h] = __expf(z - mh[h]) * inv_s[h];
                }
                *(float4*)(alphaT[t]) = al;
            } else {
                src_ch[t] = n;
                *(float4*)(alphaT[t]) = make_float4(0.f, 0.f, 0.f, 0.f);
            }
        }
        __syncthreads();
        for (int j = wid * 2; j < mpad; j += 8) {
            int sA = __builtin_amdgcn_readfirstlane(src_ch[j]);
            int sB = __builtin_amdgcn_readfirstlane(src_ch[j + 1]);
            uint2 uA = *(const uint2*)(x_bf + (size_t)sA * HDIM + lane * 4);
            uint2 uB = *(const uint2*)(x_bf + (size_t)sB * HDIM + lane * 4);
            float4 pA = *(const float4*)(alphaT[j]);
            float4 pB = *(const float4*)(alphaT[j + 1]);
            float a0 = b2f_lo(uA.x), a1 = b2f_hi(uA.x);
            float a2 = b2f_lo(uA.y), a3 = b2f_hi(uA.y);
            float b0 = b2f_lo(uB.x), b1 = b2f_hi(uB.x);
            float b2v = b2f_lo(uB.y), b3 = b2f_hi(uB.y);
            acc[0][0] += pA.x * a0 + pB.x * b0; acc[0][1] += pA.x * a1 + pB.x * b1;
            acc[0][2] += pA.x * a2 + pB.x * b2v; acc[0][3] += pA.x * a3 + pB.x * b3;
            acc[1][0] += pA.y * a0 + pB.y * b0; acc[1][1] += pA.y * a1 + pB.y * b1;
            acc[1][2] += pA.y * a2 + pB.y * b2v; acc[1][3] += pA.y * a3 + pB.y * b3;
            acc[2][0] += pA.z * a0 + pB.z * b0; acc[2][1] += pA.z * a1 + pB.z * b1;
            acc[2][2] += pA.z * a2 + pB.z * b2v; acc[2][3] += pA.z * a3 + pB.z * b3;
            acc[3][0] += pA.w * a0 + pB.w * b0; acc[3][1] += pA.w * a1 + pB.w * b1;
            acc[3][2] += pA.w * a2 + pB.w * b2v; acc[3][3] += pA.w * a3 + pB.w * b3;
        }
        __syncthreads();
    }

    // cross-wave reduce + bf16 store
    #pragma unroll
    for (int h = 0; h < 4; h++)
        *(float4*)(&acc_sh[wid][h * 256 + lane * 4]) =
            make_float4(acc[h][0], acc[h][1], acc[h][2], acc[h][3]);
    __syncthreads();
    int p = tid * 4;
    float4 v0 = *(const float4*)(&acc_sh[0][p]);
    float4 v1 = *(const float4*)(&acc_sh[1][p]);
    float4 v2 = *(const float4*)(&acc_sh[2][p]);
    float4 v3 = *(const float4*)(&acc_sh[3][p]);
    ushort4 o;
    o.x = f2b(v0.x + v1.x + v2.x + v3.x);
    o.y = f2b(v0.y + v1.y + v2.y + v3.y);
    o.z = f2b(v0.z + v1.z + v2.z + v3.z);
    o.w = f2b(v0.w + v1.w + v2.w + v3.w);
    *(ushort4*)(agg + (size_t)n * NH + p) = o;
}

// LN(y) + residual ReLU, in-place x. One wave per node.
__global__ __launch_bounds__(256) void ln_residual(const unsigned short* __restrict__ y_bf,
                                                   const float* __restrict__ ln_g,
                                                   const float* __restrict__ ln_b,
                                                   unsigned short* __restrict__ x_bf)
{
    int n = blockIdx.x * 4 + (threadIdx.x >> 6);
    int lane = threadIdx.x & 63;
    ushort4 yv = *(const ushort4*)(y_bf + (size_t)n * HDIM + lane * 4);
    float y0 = b2f(yv.x), y1 = b2f(yv.y), y2 = b2f(yv.z), y3 = b2f(yv.w);
    float s1 = y0 + y1 + y2 + y3;
    float s2 = y0 * y0 + y1 * y1 + y2 * y2 + y3 * y3;
    #pragma unroll
    for (int off = 32; off > 0; off >>= 1) {
        s1 += __shfl_xor(s1, off, 64);
        s2 += __shfl_xor(s2, off, 64);
    }
    float mu = s1 * (1.f / HDIM);
    float var = s2 * (1.f / HDIM) - mu * mu;
    float rsig = rsqrtf(var + 1e-5f);
    float4 g = *(const float4*)(ln_g + lane * 4);
    float4 b = *(const float4*)(ln_b + lane * 4);
    ushort4 xv = *(const ushort4*)(x_bf + (size_t)n * HDIM + lane * 4);
    ushort4 o;
    o.x = f2b(fmaxf(b2f(xv.x) + g.x * (y0 - mu) * rsig + b.x, 0.f));
    o.y = f2b(fmaxf(b2f(xv.y) + g.y * (y1 - mu) * rsig + b.y, 0.f));
    o.z = f2b(fmaxf(b2f(xv.z) + g.z * (y2 - mu) * rsig + b.z, 0.f));
    o.w = f2b(fmaxf(b2f(xv.w) + g.w * (y3 - mu) * rsig + b.w, 0.f));
    *(ushort4*)(x_bf + (size_t)n * HDIM + lane * 4) = o;
}

__global__ __launch_bounds__(256) void head2_kernel(const unsigned short* __restrict__ hmid,
                                                    const float* __restrict__ w2,
                                                    const float* __restrict__ b2,
                                                    float* __restrict__ out)
{
    int gw = blockIdx.x * 4 + (threadIdx.x >> 6);
    int lane = threadIdx.x & 63;
    int n = gw >> 2;
    int k = gw & 3;
    const unsigned short* hr = hmid + (size_t)n * 512 + k * 128;
    const float* wr = w2 + k * 128;
    float s = b2f(hr[lane]) * wr[lane] + b2f(hr[lane + 64]) * wr[lane + 64];
    s = wave_reduce_sum(s);
    if (lane == 0) {
        s += b2[k];
        if (k == 0 || k == 3) s = 1.f / (1.f + __expf(-s));
        out[(size_t)k * N_NODES + n] = s;
    }
}

__global__ void copy_emb(const unsigned short* __restrict__ x_bf, float* __restrict__ out) {
    int i = blockIdx.x * 256 + threadIdx.x;
    ushort4 v = ((const ushort4*)x_bf)[i];
    float4 o = make_float4(b2f(v.x), b2f(v.y), b2f(v.z), b2f(v.w));
    ((float4*)out)[i] = o;
}

extern "C" void kernel_launch(void* const* d_in, const int* in_sizes, int n_in,
                              void* d_out, int out_size, void* d_ws, size_t ws_size,
                              hipStream_t stream) {
    const float* node_features = (const float*)d_in[0];
    const float* edge_attr     = (const float*)d_in[1];
    const float* enc_w         = (const float*)d_in[2];
    const float* enc_b         = (const float*)d_in[3];
    const float* edge_enc_w    = (const float*)d_in[4];
    const float* edge_enc_b    = (const float*)d_in[5];
    const float* gat_w         = (const float*)d_in[6];
    const float* att_src       = (const float*)d_in[7];
    const float* att_dst       = (const float*)d_in[8];
    const float* att_edge      = (const float*)d_in[9];
    const float* lin_edge_w    = (const float*)d_in[10];
    const float* gat_b         = (const float*)d_in[11];
    const float* ln_g          = (const float*)d_in[12];
    const float* ln_b          = (const float*)d_in[13];
    const float* head_w1       = (const float*)d_in[14];
    const float* head_b1       = (const float*)d_in[15];
    const float* head_w2       = (const float*)d_in[16];
    const float* head_b2       = (const float*)d_in[17];
    const int*   edge_index    = (const int*)d_in[18];
    const int* src0 = edge_index;
    const int* dst0 = edge_index + N_EDGES;
    float* out = (float*)d_out;

    char* cur = (char*)d_ws;
    auto alloc = [&](size_t bytes) { char* p = cur; cur += (bytes + 255) & ~(size_t)255; return p; };
    unsigned short* x_bf   = (unsigned short*)alloc((size_t)N_NODES * HDIM * 2);
    unsigned short* agg    = (unsigned short*)alloc((size_t)N_NODES * NH * 2);   // also hmid
    unsigned short* y_bf   = (unsigned short*)alloc((size_t)N_NODES * HDIM * 2);
    unsigned short* nf_bf  = (unsigned short*)alloc((size_t)N_NODES * NDIM * 2);
    unsigned short* enc_wt = (unsigned short*)alloc((size_t)HDIM * NDIM * 2);
    unsigned short* gw2t   = (unsigned short*)alloc((size_t)NLAYERS * NH * HDIM * 2);
    unsigned short* hw1t   = (unsigned short*)alloc((size_t)512 * HDIM * 2);
    float* ws_s   = (float*)alloc((size_t)NLAYERS * 4 * HDIM * 4);
    float* ws_d   = (float*)alloc((size_t)NLAYERS * 4 * HDIM * 4);
    float* a_s    = (float*)alloc((size_t)N_NODES * 4 * 4);
    float* a_d    = (float*)alloc((size_t)N_NODES * 4 * 4);
    float* ew3    = (float*)alloc((size_t)3 * N_EDGES * 4);
    float* loopw3 = (float*)alloc((size_t)3 * N_NODES * 4);
    float* wmean3 = (float*)alloc(192 * 4);
    float* scal3  = (float*)alloc(24 * 4);
    // cnt+fillc contiguous: single memset must cover both exactly (R2 lesson)
    int* cnt      = (int*)alloc((size_t)2 * N_NODES * 4);
    int* fillc    = cnt + N_NODES;
    int* row_ptr  = (int*)alloc((size_t)(N_NODES + 1) * 4);
    int* edge_ids = (int*)alloc((size_t)N_EDGES * 4);
    unsigned short* hmid = agg;

    hipMemsetAsync(cnt, 0, (size_t)2 * N_NODES * sizeof(int), stream);

    hist_kernel<<<(N_EDGES + 255) / 256, 256, 0, stream>>>(dst0, cnt);
    scan_kernel<<<1, 256, 0, stream>>>(cnt, row_ptr);
    fill_kernel<<<(N_EDGES + 255) / 256, 256, 0, stream>>>(dst0, row_ptr, fillc, edge_ids);

    conv_bf<<<(N_NODES * NDIM / 4) / 256, 256, 0, stream>>>(node_features, nf_bf);
    transpose_bf<<<dim3(HDIM / 32, NDIM / 32, 1), dim3(32, 8), 0, stream>>>(
        enc_w, enc_wt, NDIM, HDIM, 0, 0);
    gat_w_prep<<<dim3(8, 8, 12), dim3(32, 8), 0, stream>>>(gat_w, gw2t);
    ws_prep<<<12, 256, 0, stream>>>(gat_w, att_src, att_dst, ws_s, ws_d);
    transpose_bf<<<dim3(128 / 32, HDIM / 32, 4), dim3(32, 8), 0, stream>>>(
        head_w1, hw1t, HDIM, 128, (size_t)HDIM * 128, (size_t)128 * HDIM);

    layer_prep3<<<3, 128, 0, stream>>>(edge_enc_w, edge_enc_b, lin_edge_w, att_edge, wmean3, scal3);
    edge_weights_all<<<N_EDGES / 4, 256, 0, stream>>>(edge_attr, wmean3, scal3, ew3);
    loop_weights_all<<<(N_NODES + 255) / 256, 256, 0, stream>>>(ew3, row_ptr, edge_ids, loopw3);

    gemm_bf16<true, true><<<dim3(HDIM / 128, (N_NODES + 127) / 128), 256, 0, stream>>>(
        nf_bf, enc_wt, enc_b, x_bf, N_NODES, HDIM, NDIM);

    for (int l = 0; l < NLAYERS; l++) {
        attn_x<<<N_NODES, 256, 0, stream>>>(x_bf, ws_s + (size_t)l * 4 * HDIM,
                                            ws_d + (size_t)l * 4 * HDIM, a_s, a_d);
        gat_aggregate_x<<<N_NODES, 256, 0, stream>>>(
            x_bf, a_s, a_d, ew3 + (size_t)l * N_EDGES, loopw3 + (size_t)l * N_NODES,
            scal3 + l * 8, row_ptr, edge_ids, src0, agg);
        gemm_bf16<false, true><<<dim3(HDIM / 128, (N_NODES + 127) / 128), 256, 0, stream>>>(
            agg, gw2t + (size_t)l * NH * HDIM, gat_b + (size_t)l * HDIM, y_bf,
            N_NODES, HDIM, NH);
        ln_residual<<<N_NODES / 4, 256, 0, stream>>>(y_bf, ln_g + (size_t)l * HDIM,
                                                     ln_b + (size_t)l * HDIM, x_bf);
    }

    gemm_bf16<true, true><<<dim3(512 / 128, (N_NODES + 127) / 128), 256, 0, stream>>>(
        x_bf, hw1t, head_b1, hmid, N_NODES, 512, HDIM);
    head2_kernel<<<N_NODES, 256, 0, stream>>>(hmid, head_w2, head_b2, out);

    copy_emb<<<(N_NODES * HDIM / 4) / 256, 256, 0, stream>>>(x_bf, out + 4 * N_NODES);
}

// Round 7
// 596.034 us; speedup vs baseline: 1.2464x; 1.2464x over previous
//
#include <hip/hip_runtime.h>
#include <math.h>

#define N_NODES 20000
#define N_EDGES 200000
#define NDIM 128
#define EDIM 64
#define HDIM 256
#define HEADS 4
#define NH 1024
#define NLAYERS 3

typedef __attribute__((ext_vector_type(8))) short short8;
typedef __attribute__((ext_vector_type(4))) float floatx4;

__device__ __forceinline__ float b2f(unsigned short u) {
    union { unsigned u; float f; } c; c.u = ((unsigned)u) << 16; return c.f;
}
__device__ __forceinline__ float b2f_lo(unsigned u) {
    union { unsigned u; float f; } c; c.u = u << 16; return c.f;
}
__device__ __forceinline__ float b2f_hi(unsigned u) {
    union { unsigned u; float f; } c; c.u = u & 0xffff0000u; return c.f;
}
__device__ __forceinline__ unsigned short f2b(float f) {
    union { float f; unsigned u; } c; c.f = f;
    unsigned u = c.u;
    return (unsigned short)((u + 0x7FFFu + ((u >> 16) & 1u)) >> 16);
}

__device__ __forceinline__ float wave_reduce_sum(float v) {
    #pragma unroll
    for (int off = 32; off > 0; off >>= 1) v += __shfl_down(v, off, 64);
    return v;
}

// ---------------- CSR build ----------------
__global__ void hist_kernel(const int* __restrict__ dst0, int* __restrict__ cnt) {
    int e = blockIdx.x * 256 + threadIdx.x;
    if (e < N_EDGES) atomicAdd(&cnt[dst0[e]], 1);
}

__global__ void scan_kernel(const int* __restrict__ cnt, int* __restrict__ row_ptr) {
    __shared__ int wsum[4];
    __shared__ int carry_sh;
    int tid = threadIdx.x, lane = tid & 63, wid = tid >> 6;
    if (tid == 0) carry_sh = 0;
    __syncthreads();
    for (int base = 0; base < N_NODES; base += 256) {
        int v = (base + tid < N_NODES) ? cnt[base + tid] : 0;
        int s = v;
        #pragma unroll
        for (int off = 1; off < 64; off <<= 1) {
            int t = __shfl_up(s, off, 64);
            if (lane >= off) s += t;
        }
        if (lane == 63) wsum[wid] = s;
        int carry = carry_sh;
        __syncthreads();
        int woff = 0;
        for (int w = 0; w < wid; w++) woff += wsum[w];
        int incl = s + woff;
        if (base + tid < N_NODES) row_ptr[base + tid] = carry + incl - v;
        __syncthreads();
        if (tid == 255) carry_sh = carry + incl;
        __syncthreads();
    }
    if (tid == 0) row_ptr[N_NODES] = carry_sh;
}

// fill CSR position arrays: srcCSR/dstCSR (pos-indexed), pose (edge->pos)
__global__ void fill_kernel(const int* __restrict__ src0, const int* __restrict__ dst0,
                            const int* __restrict__ row_ptr, int* __restrict__ fillc,
                            int* __restrict__ srcCSR, int* __restrict__ dstCSR,
                            int* __restrict__ pose) {
    int e = blockIdx.x * 256 + threadIdx.x;
    if (e < N_EDGES) {
        int d = dst0[e];
        int p = atomicAdd(&fillc[d], 1);
        int pos = row_ptr[d] + p;
        srcCSR[pos] = src0[e];
        dstCSR[pos] = d;
        pose[e] = pos;
    }
}

// ---------------- weight prep ----------------
__global__ void transpose_bf(const float* __restrict__ in, unsigned short* __restrict__ out,
                             int K, int Nn, size_t in_bs, size_t out_bs) {
    in += blockIdx.z * in_bs;
    out += blockIdx.z * out_bs;
    __shared__ float sh[32][33];
    int tx = threadIdx.x, ty = threadIdx.y;
    int kb = blockIdx.y * 32, nb = blockIdx.x * 32;
    #pragma unroll
    for (int i = 0; i < 32; i += 8)
        sh[ty + i][tx] = in[(size_t)(kb + ty + i) * Nn + nb + tx];
    __syncthreads();
    #pragma unroll
    for (int i = 0; i < 32; i += 8)
        out[(size_t)(nb + ty + i) * K + kb + tx] = f2b(sh[tx][ty + i]);
}

// gw2t[l][d][h*256+k] = gat_w[l][k][h*256+d] * 0.25 (head-mean folded in)
__global__ void gat_w_prep(const float* __restrict__ in, unsigned short* __restrict__ out) {
    int z = blockIdx.z, l = z >> 2, h = z & 3;
    __shared__ float sh[32][33];
    int tx = threadIdx.x, ty = threadIdx.y;
    int kb = blockIdx.y * 32, db = blockIdx.x * 32;
    const float* src = in + (size_t)l * HDIM * NH + (size_t)h * HDIM;
    unsigned short* dst = out + (size_t)l * HDIM * NH + (size_t)h * HDIM;
    #pragma unroll
    for (int i = 0; i < 32; i += 8)
        sh[ty + i][tx] = src[(size_t)(kb + ty + i) * NH + db + tx];
    __syncthreads();
    #pragma unroll
    for (int i = 0; i < 32; i += 8)
        dst[(size_t)(db + ty + i) * NH + kb + tx] = f2b(0.25f * sh[tx][ty + i]);
}

// ws_s[l*4+h][k] = sum_d gat_w[l][k][h*256+d] * att_src[l][h][d]; same for dst
__global__ void ws_prep(const float* __restrict__ gat_w, const float* __restrict__ att_src,
                        const float* __restrict__ att_dst,
                        float* __restrict__ ws_s, float* __restrict__ ws_d) {
    int l = blockIdx.x >> 2, h = blockIdx.x & 3;
    int k = threadIdx.x;
    const float* wrow = gat_w + (size_t)l * HDIM * NH + (size_t)k * NH + h * HDIM;
    const float* as = att_src + (size_t)l * NH + h * HDIM;
    const float* ad = att_dst + (size_t)l * NH + h * HDIM;
    float s1 = 0.f, s2 = 0.f;
    for (int d = 0; d < HDIM; d += 4) {
        float4 w4 = *(const float4*)(wrow + d);
        float4 a4 = *(const float4*)(as + d);
        float4 b4 = *(const float4*)(ad + d);
        s1 += w4.x * a4.x + w4.y * a4.y + w4.z * a4.z + w4.w * a4.w;
        s2 += w4.x * b4.x + w4.y * b4.y + w4.z * b4.z + w4.w * b4.w;
    }
    ws_s[(size_t)blockIdx.x * HDIM + k] = s1;
    ws_d[(size_t)blockIdx.x * HDIM + k] = s2;
}

__global__ void conv_bf(const float* __restrict__ in, unsigned short* __restrict__ out) {
    int i = blockIdx.x * 256 + threadIdx.x;
    float4 v = ((const float4*)in)[i];
    ushort4 o;
    o.x = f2b(v.x); o.y = f2b(v.y); o.z = f2b(v.z); o.w = f2b(v.w);
    ((ushort4*)out)[i] = o;
}

// ---------------- bf16 MFMA GEMM ----------------
template <bool RELU, bool BIAS>
__global__ __launch_bounds__(256) void gemm_bf16(
    const unsigned short* __restrict__ A, const unsigned short* __restrict__ Bt,
    const float* __restrict__ bias, unsigned short* __restrict__ C,
    int M, int Ntot, int K)
{
    __shared__ char lds[32768];
    unsigned short* As = (unsigned short*)lds;
    unsigned short* Bs = (unsigned short*)(lds + 8192);
    unsigned short* Cs = (unsigned short*)lds;

    int tid = threadIdx.x;
    int lane = tid & 63;
    int wid = tid >> 6;
    int row0 = blockIdx.y * 128;
    int col0 = blockIdx.x * 128;
    int wm = (wid >> 1) * 64;
    int wn = (wid & 1) * 64;
    int lm = lane & 15;
    int q8 = (lane >> 4) * 8;
    int q4 = (lane >> 4) * 4;

    floatx4 acc[4][4];
    #pragma unroll
    for (int i = 0; i < 4; i++)
        #pragma unroll
        for (int j = 0; j < 4; j++)
            acc[i][j] = (floatx4)(0.f);

    for (int k0 = 0; k0 < K; k0 += 32) {
        #pragma unroll
        for (int r = 0; r < 2; r++) {
            int chunk = tid + r * 256;
            int arow = chunk >> 2;
            int acol = (chunk & 3) * 8;
            int garow = row0 + arow; if (garow > M - 1) garow = M - 1;
            __builtin_amdgcn_global_load_lds(
                (__attribute__((address_space(1))) const void*)(A + (size_t)garow * K + k0 + acol),
                (__attribute__((address_space(3))) void*)(As + chunk * 8), 16, 0, 0);
            __builtin_amdgcn_global_load_lds(
                (__attribute__((address_space(1))) const void*)(Bt + (size_t)(col0 + arow) * K + k0 + acol),
                (__attribute__((address_space(3))) void*)(Bs + chunk * 8), 16, 0, 0);
        }
        __syncthreads();
        short8 af[4], bf[4];
        #pragma unroll
        for (int i = 0; i < 4; i++)
            af[i] = *(const short8*)(As + (wm + i * 16 + lm) * 32 + q8);
        #pragma unroll
        for (int j = 0; j < 4; j++)
            bf[j] = *(const short8*)(Bs + (wn + j * 16 + lm) * 32 + q8);
        #pragma unroll
        for (int i = 0; i < 4; i++)
            #pragma unroll
            for (int j = 0; j < 4; j++)
                acc[i][j] = __builtin_amdgcn_mfma_f32_16x16x32_bf16(af[i], bf[j], acc[i][j], 0, 0, 0);
        __syncthreads();
    }

    #pragma unroll
    for (int i = 0; i < 4; i++) {
        #pragma unroll
        for (int j = 0; j < 4; j++) {
            int cl = wn + j * 16 + lm;
            float bv = BIAS ? bias[col0 + cl] : 0.f;
            #pragma unroll
            for (int reg = 0; reg < 4; reg++) {
                int rl = wm + i * 16 + q4 + reg;
                float v = acc[i][j][reg];
                if (BIAS) v += bv;
                if (RELU) v = fmaxf(v, 0.f);
                Cs[rl * 128 + cl] = f2b(v);
            }
        }
    }
    __syncthreads();
    int row = tid >> 1;
    int ce = (tid & 1) * 64;
    if (row0 + row < M) {
        #pragma unroll
        for (int u = 0; u < 8; u++) {
            int4 v = *(const int4*)(Cs + row * 128 + ce + u * 8);
            *(int4*)(C + (size_t)(row0 + row) * Ntot + col0 + ce + u * 8) = v;
        }
    }
}

// ---------------- per-layer small precompute ----------------
__global__ void layer_prep3(const float* __restrict__ edge_enc_w, const float* __restrict__ edge_enc_b,
                            const float* __restrict__ lin_edge_w, const float* __restrict__ att_edge,
                            float* __restrict__ wmean3, float* __restrict__ scal3)
{
    int l = blockIdx.x;
    const float* eew = edge_enc_w + (size_t)l * EDIM * HDIM;
    const float* eeb = edge_enc_b + (size_t)l * HDIM;
    const float* lew = lin_edge_w + (size_t)l * NH;
    const float* ae  = att_edge + (size_t)l * NH;
    float* wm = wmean3 + l * 64;
    float* sc = scal3 + l * 8;
    int tid = threadIdx.x;
    if (tid < 64) {
        float s = 0.f;
        for (int d = 0; d < HDIM; d++) s += eew[tid * HDIM + d];
        wm[tid] = s * (1.f / HDIM);
    } else if (tid < 68) {
        int h = tid - 64;
        float s = 0.f;
        for (int d = 0; d < HDIM; d++) s += lew[h * HDIM + d] * ae[h * HDIM + d];
        sc[h] = s;
    } else if (tid == 68) {
        float s = 0.f;
        for (int d = 0; d < HDIM; d++) s += eeb[d];
        sc[4] = s * (1.f / HDIM);
    }
}

// ew for all 3 layers, scattered into CSR position order via pose[e]
__global__ __launch_bounds__(256) void edge_weights_all(const float* __restrict__ edge_attr,
                                                        const float* __restrict__ wmean3,
                                                        const float* __restrict__ scal3,
                                                        const int* __restrict__ pose,
                                                        float* __restrict__ ewCSR3)
{
    int e = blockIdx.x * 4 + (threadIdx.x >> 6);
    int lane = threadIdx.x & 63;
    float a = edge_attr[(size_t)e * EDIM + lane];
    float v0 = a * wmean3[lane];
    float v1 = a * wmean3[64 + lane];
    float v2 = a * wmean3[128 + lane];
    #pragma unroll
    for (int off = 32; off > 0; off >>= 1) {
        v0 += __shfl_down(v0, off, 64);
        v1 += __shfl_down(v1, off, 64);
        v2 += __shfl_down(v2, off, 64);
    }
    if (lane == 0) {
        int pos = pose[e];
        ewCSR3[pos] = v0 + scal3[4];
        ewCSR3[N_EDGES + pos] = v1 + scal3[12];
        ewCSR3[2 * N_EDGES + pos] = v2 + scal3[20];
    }
}

__global__ void loop_weights_all(const float* __restrict__ ewCSR3, const int* __restrict__ row_ptr,
                                 float* __restrict__ loopw3)
{
    int n = blockIdx.x * 256 + threadIdx.x;
    if (n >= N_NODES) return;
    int r0 = row_ptr[n], r1 = row_ptr[n + 1];
    float s0 = 0.f, s1 = 0.f, s2 = 0.f;
    for (int i = r0; i < r1; i++) {
        s0 += ewCSR3[i]; s1 += ewCSR3[N_EDGES + i]; s2 += ewCSR3[2 * N_EDGES + i];
    }
    float inv = 1.f / fmaxf((float)(r1 - r0), 1.f);
    loopw3[n] = s0 * inv;
    loopw3[N_NODES + n] = s1 * inv;
    loopw3[2 * N_NODES + n] = s2 * inv;
}

// a_s/a_d from x: wave per node, 4 nodes/block
__global__ __launch_bounds__(256) void attn_x(const unsigned short* __restrict__ x_bf,
                                              const float* __restrict__ ws_s,
                                              const float* __restrict__ ws_d,
                                              float* __restrict__ a_s,
                                              float* __restrict__ a_d)
{
    int wid = threadIdx.x >> 6, lane = threadIdx.x & 63;
    int n = blockIdx.x * 4 + wid;
    ushort4 xv = *(const ushort4*)(x_bf + (size_t)n * HDIM + lane * 4);
    float x0 = b2f(xv.x), x1 = b2f(xv.y), x2 = b2f(xv.z), x3 = b2f(xv.w);
    float ss[4], sd[4];
    #pragma unroll
    for (int h = 0; h < 4; h++) {
        float4 s4 = *(const float4*)(ws_s + h * HDIM + lane * 4);
        float4 d4 = *(const float4*)(ws_d + h * HDIM + lane * 4);
        ss[h] = x0 * s4.x + x1 * s4.y + x2 * s4.z + x3 * s4.w;
        sd[h] = x0 * d4.x + x1 * d4.y + x2 * d4.z + x3 * d4.w;
    }
    #pragma unroll
    for (int off = 32; off > 0; off >>= 1)
        #pragma unroll
        for (int h = 0; h < 4; h++) {
            ss[h] += __shfl_xor(ss[h], off, 64);
            sd[h] += __shfl_xor(sd[h], off, 64);
        }
    if (lane == 0) {
        *(float4*)(a_s + n * 4) = make_float4(ss[0], ss[1], ss[2], ss[3]);
        *(float4*)(a_d + n * 4) = make_float4(sd[0], sd[1], sd[2], sd[3]);
    }
}

// z[pos][h] = leaky_relu(a_s[src] + a_d[dst] + c[h]*ew), CSR order, coalesced
__global__ __launch_bounds__(256) void edge_logits(const int* __restrict__ srcCSR,
                                                   const int* __restrict__ dstCSR,
                                                   const float* __restrict__ ewCSR,
                                                   const float* __restrict__ a_s,
                                                   const float* __restrict__ a_d,
                                                   const float* __restrict__ scal,
                                                   float* __restrict__ zCSR)
{
    int pos = blockIdx.x * 256 + threadIdx.x;
    if (pos >= N_EDGES) return;
    int sn = srcCSR[pos], dn = dstCSR[pos];
    float w = ewCSR[pos];
    float4 c4 = *(const float4*)scal;
    float4 zs = *(const float4*)(a_s + sn * 4);
    float4 zd = *(const float4*)(a_d + dn * 4);
    float4 z;
    z.x = zs.x + zd.x + c4.x * w; z.x = z.x > 0.f ? z.x : 0.2f * z.x;
    z.y = zs.y + zd.y + c4.y * w; z.y = z.y > 0.f ? z.y : 0.2f * z.y;
    z.z = zs.z + zd.z + c4.z * w; z.z = z.z > 0.f ? z.z : 0.2f * z.z;
    z.w = zs.w + zd.w + c4.w * w; z.w = z.w > 0.f ? z.w : 0.2f * z.w;
    ((float4*)zCSR)[pos] = z;
}

// Wave-per-node softmax + aggregate. 4 nodes/block, no __syncthreads.
// Lane L caches z/src of CSR element r0+L; butterflies for stats; inner loop
// pulls element j's z/src from lane j via __shfl (wave-uniform j).
__global__ __launch_bounds__(256) void gat_agg_wave(
    const unsigned short* __restrict__ x_bf, const float* __restrict__ a_s,
    const float* __restrict__ a_d, const float* __restrict__ loopw,
    const float* __restrict__ scal, const int* __restrict__ row_ptr,
    const int* __restrict__ srcCSR, const float* __restrict__ zCSR,
    unsigned short* __restrict__ agg)
{
    int wid = threadIdx.x >> 6, lane = threadIdx.x & 63;
    int n = blockIdx.x * 4 + wid;
    int r0 = row_ptr[n];
    int deg = row_ptr[n + 1] - r0;
    int cnt = deg + 1;

    float4 c4 = *(const float4*)scal;
    float4 as = *(const float4*)(a_s + n * 4);
    float4 ad = *(const float4*)(a_d + n * 4);
    float lw = loopw[n];
    float4 zself;
    zself.x = as.x + ad.x + c4.x * lw; zself.x = zself.x > 0.f ? zself.x : 0.2f * zself.x;
    zself.y = as.y + ad.y + c4.y * lw; zself.y = zself.y > 0.f ? zself.y : 0.2f * zself.y;
    zself.z = as.z + ad.z + c4.z * lw; zself.z = zself.z > 0.f ? zself.z : 0.2f * zself.z;
    zself.w = as.w + ad.w + c4.w * lw; zself.w = zself.w > 0.f ? zself.w : 0.2f * zself.w;

    auto load_z = [&](int c0) -> float4 {
        int idx = c0 + lane;
        if (idx < deg) return ((const float4*)zCSR)[r0 + idx];
        if (idx == deg) return zself;
        return make_float4(-1e30f, -1e30f, -1e30f, -1e30f);
    };
    auto load_s = [&](int c0) -> int {
        int idx = c0 + lane;
        return (idx < deg) ? srcCSR[r0 + idx] : n;
    };

    float4 zc0 = load_z(0);
    int sv0 = load_s(0);

    // stats pass 1: max
    float m0 = zc0.x, m1 = zc0.y, m2 = zc0.z, m3 = zc0.w;
    for (int c0 = 64; c0 < cnt; c0 += 64) {
        float4 z = load_z(c0);
        m0 = fmaxf(m0, z.x); m1 = fmaxf(m1, z.y);
        m2 = fmaxf(m2, z.z); m3 = fmaxf(m3, z.w);
    }
    #pragma unroll
    for (int off = 32; off > 0; off >>= 1) {
        m0 = fmaxf(m0, __shfl_xor(m0, off, 64));
        m1 = fmaxf(m1, __shfl_xor(m1, off, 64));
        m2 = fmaxf(m2, __shfl_xor(m2, off, 64));
        m3 = fmaxf(m3, __shfl_xor(m3, off, 64));
    }
    // stats pass 2: sum exp
    float s0 = __expf(zc0.x - m0), s1 = __expf(zc0.y - m1);
    float s2 = __expf(zc0.z - m2), s3 = __expf(zc0.w - m3);
    for (int c0 = 64; c0 < cnt; c0 += 64) {
        float4 z = load_z(c0);
        s0 += __expf(z.x - m0); s1 += __expf(z.y - m1);
        s2 += __expf(z.z - m2); s3 += __expf(z.w - m3);
    }
    #pragma unroll
    for (int off = 32; off > 0; off >>= 1) {
        s0 += __shfl_xor(s0, off, 64);
        s1 += __shfl_xor(s1, off, 64);
        s2 += __shfl_xor(s2, off, 64);
        s3 += __shfl_xor(s3, off, 64);
    }
    float i0 = 1.f / s0, i1 = 1.f / s1, i2 = 1.f / s2, i3 = 1.f / s3;

    // aggregation
    float acc[4][4] = {};
    const unsigned short* xw = x_bf + (size_t)lane * 4;
    for (int c0 = 0; c0 < cnt; c0 += 64) {
        float4 z = (c0 == 0) ? zc0 : load_z(c0);
        int sv = (c0 == 0) ? sv0 : load_s(c0);
        int mc = min(64, cnt - c0);
        int j = 0;
        for (; j + 1 < mc; j += 2) {
            int sA = __builtin_amdgcn_readfirstlane(__shfl(sv, j, 64));
            int sB = __builtin_amdgcn_readfirstlane(__shfl(sv, j + 1, 64));
            uint2 uA = *(const uint2*)(xw + (size_t)sA * HDIM);
            uint2 uB = *(const uint2*)(xw + (size_t)sB * HDIM);
            float aA0 = __expf(__shfl(z.x, j, 64) - m0) * i0;
            float aA1 = __expf(__shfl(z.y, j, 64) - m1) * i1;
            float aA2 = __expf(__shfl(z.z, j, 64) - m2) * i2;
            float aA3 = __expf(__shfl(z.w, j, 64) - m3) * i3;
            float aB0 = __expf(__shfl(z.x, j + 1, 64) - m0) * i0;
            float aB1 = __expf(__shfl(z.y, j + 1, 64) - m1) * i1;
            float aB2 = __expf(__shfl(z.z, j + 1, 64) - m2) * i2;
            float aB3 = __expf(__shfl(z.w, j + 1, 64) - m3) * i3;
            float xa0 = b2f_lo(uA.x), xa1 = b2f_hi(uA.x), xa2 = b2f_lo(uA.y), xa3 = b2f_hi(uA.y);
            float xb0 = b2f_lo(uB.x), xb1 = b2f_hi(uB.x), xb2 = b2f_lo(uB.y), xb3 = b2f_hi(uB.y);
            acc[0][0] += aA0 * xa0 + aB0 * xb0; acc[0][1] += aA0 * xa1 + aB0 * xb1;
            acc[0][2] += aA0 * xa2 + aB0 * xb2; acc[0][3] += aA0 * xa3 + aB0 * xb3;
            acc[1][0] += aA1 * xa0 + aB1 * xb0; acc[1][1] += aA1 * xa1 + aB1 * xb1;
            acc[1][2] += aA1 * xa2 + aB1 * xb2; acc[1][3] += aA1 * xa3 + aB1 * xb3;
            acc[2][0] += aA2 * xa0 + aB2 * xb0; acc[2][1] += aA2 * xa1 + aB2 * xb1;
            acc[2][2] += aA2 * xa2 + aB2 * xb2; acc[2][3] += aA2 * xa3 + aB2 * xb3;
            acc[3][0] += aA3 * xa0 + aB3 * xb0; acc[3][1] += aA3 * xa1 + aB3 * xb1;
            acc[3][2] += aA3 * xa2 + aB3 * xb2; acc[3][3] += aA3 * xa3 + aB3 * xb3;
        }
        if (j < mc) {
            int sA = __builtin_amdgcn_readfirstlane(__shfl(sv, j, 64));
            uint2 uA = *(const uint2*)(xw + (size_t)sA * HDIM);
            float aA0 = __expf(__shfl(z.x, j, 64) - m0) * i0;
            float aA1 = __expf(__shfl(z.y, j, 64) - m1) * i1;
            float aA2 = __expf(__shfl(z.z, j, 64) - m2) * i2;
            float aA3 = __expf(__shfl(z.w, j, 64) - m3) * i3;
            float xa0 = b2f_lo(uA.x), xa1 = b2f_hi(uA.x), xa2 = b2f_lo(uA.y), xa3 = b2f_hi(uA.y);
            acc[0][0] += aA0 * xa0; acc[0][1] += aA0 * xa1; acc[0][2] += aA0 * xa2; acc[0][3] += aA0 * xa3;
            acc[1][0] += aA1 * xa0; acc[1][1] += aA1 * xa1; acc[1][2] += aA1 * xa2; acc[1][3] += aA1 * xa3;
            acc[2][0] += aA2 * xa0; acc[2][1] += aA2 * xa1; acc[2][2] += aA2 * xa2; acc[2][3] += aA2 * xa3;
            acc[3][0] += aA3 * xa0; acc[3][1] += aA3 * xa1; acc[3][2] += aA3 * xa2; acc[3][3] += aA3 * xa3;
        }
    }

    unsigned short* ag = agg + (size_t)n * NH + lane * 4;
    #pragma unroll
    for (int h = 0; h < 4; h++) {
        ushort4 o;
        o.x = f2b(acc[h][0]); o.y = f2b(acc[h][1]);
        o.z = f2b(acc[h][2]); o.w = f2b(acc[h][3]);
        *(ushort4*)(ag + h * 256) = o;
    }
}

// LN(y) + residual ReLU, in-place x. One wave per node.
__global__ __launch_bounds__(256) void ln_residual(const unsigned short* __restrict__ y_bf,
                                                   const float* __restrict__ ln_g,
                                                   const float* __restrict__ ln_b,
                                                   unsigned short* __restrict__ x_bf)
{
    int n = blockIdx.x * 4 + (threadIdx.x >> 6);
    int lane = threadIdx.x & 63;
    ushort4 yv = *(const ushort4*)(y_bf + (size_t)n * HDIM + lane * 4);
    float y0 = b2f(yv.x), y1 = b2f(yv.y), y2 = b2f(yv.z), y3 = b2f(yv.w);
    float s1 = y0 + y1 + y2 + y3;
    float s2 = y0 * y0 + y1 * y1 + y2 * y2 + y3 * y3;
    #pragma unroll
    for (int off = 32; off > 0; off >>= 1) {
        s1 += __shfl_xor(s1, off, 64);
        s2 += __shfl_xor(s2, off, 64);
    }
    float mu = s1 * (1.f / HDIM);
    float var = s2 * (1.f / HDIM) - mu * mu;
    float rsig = rsqrtf(var + 1e-5f);
    float4 g = *(const float4*)(ln_g + lane * 4);
    float4 b = *(const float4*)(ln_b + lane * 4);
    ushort4 xv = *(const ushort4*)(x_bf + (size_t)n * HDIM + lane * 4);
    ushort4 o;
    o.x = f2b(fmaxf(b2f(xv.x) + g.x * (y0 - mu) * rsig + b.x, 0.f));
    o.y = f2b(fmaxf(b2f(xv.y) + g.y * (y1 - mu) * rsig + b.y, 0.f));
    o.z = f2b(fmaxf(b2f(xv.z) + g.z * (y2 - mu) * rsig + b.z, 0.f));
    o.w = f2b(fmaxf(b2f(xv.w) + g.w * (y3 - mu) * rsig + b.w, 0.f));
    *(ushort4*)(x_bf + (size_t)n * HDIM + lane * 4) = o;
}

__global__ __launch_bounds__(256) void head2_kernel(const unsigned short* __restrict__ hmid,
                                                    const float* __restrict__ w2,
                                                    const float* __restrict__ b2,
                                                    float* __restrict__ out)
{
    int gw = blockIdx.x * 4 + (threadIdx.x >> 6);
    int lane = threadIdx.x & 63;
    int n = gw >> 2;
    int k = gw & 3;
    const unsigned short* hr = hmid + (size_t)n * 512 + k * 128;
    const float* wr = w2 + k * 128;
    float s = b2f(hr[lane]) * wr[lane] + b2f(hr[lane + 64]) * wr[lane + 64];
    s = wave_reduce_sum(s);
    if (lane == 0) {
        s += b2[k];
        if (k == 0 || k == 3) s = 1.f / (1.f + __expf(-s));
        out[(size_t)k * N_NODES + n] = s;
    }
}

__global__ void copy_emb(const unsigned short* __restrict__ x_bf, float* __restrict__ out) {
    int i = blockIdx.x * 256 + threadIdx.x;
    ushort4 v = ((const ushort4*)x_bf)[i];
    float4 o = make_float4(b2f(v.x), b2f(v.y), b2f(v.z), b2f(v.w));
    ((float4*)out)[i] = o;
}

extern "C" void kernel_launch(void* const* d_in, const int* in_sizes, int n_in,
                              void* d_out, int out_size, void* d_ws, size_t ws_size,
                              hipStream_t stream) {
    const float* node_features = (const float*)d_in[0];
    const float* edge_attr     = (const float*)d_in[1];
    const float* enc_w         = (const float*)d_in[2];
    const float* enc_b         = (const float*)d_in[3];
    const float* edge_enc_w    = (const float*)d_in[4];
    const float* edge_enc_b    = (const float*)d_in[5];
    const float* gat_w         = (const float*)d_in[6];
    const float* att_src       = (const float*)d_in[7];
    const float* att_dst       = (const float*)d_in[8];
    const float* att_edge      = (const float*)d_in[9];
    const float* lin_edge_w    = (const float*)d_in[10];
    const float* gat_b         = (const float*)d_in[11];
    const float* ln_g          = (const float*)d_in[12];
    const float* ln_b          = (const float*)d_in[13];
    const float* head_w1       = (const float*)d_in[14];
    const float* head_b1       = (const float*)d_in[15];
    const float* head_w2       = (const float*)d_in[16];
    const float* head_b2       = (const float*)d_in[17];
    const int*   edge_index    = (const int*)d_in[18];
    const int* src0 = edge_index;
    const int* dst0 = edge_index + N_EDGES;
    float* out = (float*)d_out;

    char* cur = (char*)d_ws;
    auto alloc = [&](size_t bytes) { char* p = cur; cur += (bytes + 255) & ~(size_t)255; return p; };
    unsigned short* x_bf   = (unsigned short*)alloc((size_t)N_NODES * HDIM * 2);
    unsigned short* agg    = (unsigned short*)alloc((size_t)N_NODES * NH * 2);   // also hmid
    unsigned short* y_bf   = (unsigned short*)alloc((size_t)N_NODES * HDIM * 2);
    unsigned short* nf_bf  = (unsigned short*)alloc((size_t)N_NODES * NDIM * 2);
    unsigned short* enc_wt = (unsigned short*)alloc((size_t)HDIM * NDIM * 2);
    unsigned short* gw2t   = (unsigned short*)alloc((size_t)NLAYERS * NH * HDIM * 2);
    unsigned short* hw1t   = (unsigned short*)alloc((size_t)512 * HDIM * 2);
    float* ws_s   = (float*)alloc((size_t)NLAYERS * 4 * HDIM * 4);
    float* ws_d   = (float*)alloc((size_t)NLAYERS * 4 * HDIM * 4);
    float* a_s    = (float*)alloc((size_t)N_NODES * 4 * 4);
    float* a_d    = (float*)alloc((size_t)N_NODES * 4 * 4);
    float* ewCSR3 = (float*)alloc((size_t)3 * N_EDGES * 4);
    float* loopw3 = (float*)alloc((size_t)3 * N_NODES * 4);
    float* zCSR   = (float*)alloc((size_t)N_EDGES * 4 * 4);
    float* wmean3 = (float*)alloc(192 * 4);
    float* scal3  = (float*)alloc(24 * 4);
    // cnt+fillc contiguous: single memset must cover both exactly (R2 lesson)
    int* cnt      = (int*)alloc((size_t)2 * N_NODES * 4);
    int* fillc    = cnt + N_NODES;
    int* row_ptr  = (int*)alloc((size_t)(N_NODES + 1) * 4);
    int* srcCSR   = (int*)alloc((size_t)N_EDGES * 4);
    int* dstCSR   = (int*)alloc((size_t)N_EDGES * 4);
    int* pose     = (int*)alloc((size_t)N_EDGES * 4);
    unsigned short* hmid = agg;

    hipMemsetAsync(cnt, 0, (size_t)2 * N_NODES * sizeof(int), stream);

    hist_kernel<<<(N_EDGES + 255) / 256, 256, 0, stream>>>(dst0, cnt);
    scan_kernel<<<1, 256, 0, stream>>>(cnt, row_ptr);
    fill_kernel<<<(N_EDGES + 255) / 256, 256, 0, stream>>>(src0, dst0, row_ptr, fillc,
                                                           srcCSR, dstCSR, pose);

    conv_bf<<<(N_NODES * NDIM / 4) / 256, 256, 0, stream>>>(node_features, nf_bf);
    transpose_bf<<<dim3(HDIM / 32, NDIM / 32, 1), dim3(32, 8), 0, stream>>>(
        enc_w, enc_wt, NDIM, HDIM, 0, 0);
    gat_w_prep<<<dim3(8, 8, 12), dim3(32, 8), 0, stream>>>(gat_w, gw2t);
    ws_prep<<<12, 256, 0, stream>>>(gat_w, att_src, att_dst, ws_s, ws_d);
    transpose_bf<<<dim3(128 / 32, HDIM / 32, 4), dim3(32, 8), 0, stream>>>(
        head_w1, hw1t, HDIM, 128, (size_t)HDIM * 128, (size_t)128 * HDIM);

    layer_prep3<<<3, 128, 0, stream>>>(edge_enc_w, edge_enc_b, lin_edge_w, att_edge, wmean3, scal3);
    edge_weights_all<<<N_EDGES / 4, 256, 0, stream>>>(edge_attr, wmean3, scal3, pose, ewCSR3);
    loop_weights_all<<<(N_NODES + 255) / 256, 256, 0, stream>>>(ewCSR3, row_ptr, loopw3);

    gemm_bf16<true, true><<<dim3(HDIM / 128, (N_NODES + 127) / 128), 256, 0, stream>>>(
        nf_bf, enc_wt, enc_b, x_bf, N_NODES, HDIM, NDIM);

    for (int l = 0; l < NLAYERS; l++) {
        attn_x<<<N_NODES / 4, 256, 0, stream>>>(x_bf, ws_s + (size_t)l * 4 * HDIM,
                                                ws_d + (size_t)l * 4 * HDIM, a_s, a_d);
        edge_logits<<<(N_EDGES + 255) / 256, 256, 0, stream>>>(
            srcCSR, dstCSR, ewCSR3 + (size_t)l * N_EDGES, a_s, a_d, scal3 + l * 8, zCSR);
        gat_agg_wave<<<N_NODES / 4, 256, 0, stream>>>(
            x_bf, a_s, a_d, loopw3 + (size_t)l * N_NODES, scal3 + l * 8,
            row_ptr, srcCSR, zCSR, agg);
        gemm_bf16<false, true><<<dim3(HDIM / 128, (N_NODES + 127) / 128), 256, 0, stream>>>(
            agg, gw2t + (size_t)l * NH * HDIM, gat_b + (size_t)l * HDIM, y_bf,
            N_NODES, HDIM, NH);
        ln_residual<<<N_NODES / 4, 256, 0, stream>>>(y_bf, ln_g + (size_t)l * HDIM,
                                                     ln_b + (size_t)l * HDIM, x_bf);
    }

    gemm_bf16<true, true><<<dim3(512 / 128, (N_NODES + 127) / 128), 256, 0, stream>>>(
        x_bf, hw1t, head_b1, hmid, N_NODES, 512, HDIM);
    head2_kernel<<<N_NODES, 256, 0, stream>>>(hmid, head_w2, head_b2, out);

    copy_emb<<<(N_NODES * HDIM / 4) / 256, 256, 0, stream>>>(x_bf, out + 4 * N_NODES);
}

// Round 8
// 548.594 us; speedup vs baseline: 1.3542x; 1.0865x over previous
//
#include <hip/hip_runtime.h>
#include <math.h>

#define N_NODES 20000
#define N_EDGES 200000
#define NDIM 128
#define EDIM 64
#define HDIM 256
#define HEADS 4
#define NH 1024
#define NLAYERS 3
#define SCAN_NBLK ((N_NODES + 255) / 256)   // 79

typedef __attribute__((ext_vector_type(8))) short short8;
typedef __attribute__((ext_vector_type(4))) float floatx4;

__device__ __forceinline__ float b2f(unsigned short u) {
    union { unsigned u; float f; } c; c.u = ((unsigned)u) << 16; return c.f;
}
__device__ __forceinline__ float b2f_lo(unsigned u) {
    union { unsigned u; float f; } c; c.u = u << 16; return c.f;
}
__device__ __forceinline__ float b2f_hi(unsigned u) {
    union { unsigned u; float f; } c; c.u = u & 0xffff0000u; return c.f;
}
__device__ __forceinline__ unsigned short f2b(float f) {
    union { float f; unsigned u; } c; c.f = f;
    unsigned u = c.u;
    return (unsigned short)((u + 0x7FFFu + ((u >> 16) & 1u)) >> 16);
}

__device__ __forceinline__ float wave_reduce_sum(float v) {
    #pragma unroll
    for (int off = 32; off > 0; off >>= 1) v += __shfl_down(v, off, 64);
    return v;
}

// ---------------- CSR build ----------------
__global__ void hist_kernel(const int* __restrict__ dst0, int* __restrict__ cnt) {
    int e = blockIdx.x * 256 + threadIdx.x;
    if (e < N_EDGES) atomicAdd(&cnt[dst0[e]], 1);
}

// parallel scan, stage 1: per-block exclusive scan + block totals
__global__ void scan_local(const int* __restrict__ cnt, int* __restrict__ row_ptr,
                           int* __restrict__ bsum) {
    __shared__ int wsum[4];
    int tid = threadIdx.x, lane = tid & 63, wid = tid >> 6;
    int n = blockIdx.x * 256 + tid;
    int v = (n < N_NODES) ? cnt[n] : 0;
    int s = v;
    #pragma unroll
    for (int off = 1; off < 64; off <<= 1) {
        int t = __shfl_up(s, off, 64);
        if (lane >= off) s += t;
    }
    if (lane == 63) wsum[wid] = s;
    __syncthreads();
    int woff = 0;
    #pragma unroll
    for (int w = 0; w < 4; w++) if (w < wid) woff += wsum[w];
    if (n < N_NODES) row_ptr[n] = woff + s - v;   // local exclusive
    if (tid == 255) bsum[blockIdx.x] = woff + s;
}

// stage 2: scan the (79) block totals in one block
__global__ void scan_bsums(int* __restrict__ bsum, int* __restrict__ boff) {
    __shared__ int wsum[2];
    int tid = threadIdx.x, lane = tid & 63, wid = tid >> 6;  // 128 threads
    int v = (tid < SCAN_NBLK) ? bsum[tid] : 0;
    int s = v;
    #pragma unroll
    for (int off = 1; off < 64; off <<= 1) {
        int t = __shfl_up(s, off, 64);
        if (lane >= off) s += t;
    }
    if (lane == 63) wsum[wid] = s;
    __syncthreads();
    int woff = (wid == 1) ? wsum[0] : 0;
    if (tid < SCAN_NBLK) boff[tid] = woff + s - v;   // exclusive
    if (tid == SCAN_NBLK - 1) boff[SCAN_NBLK] = woff + s;  // total
}

// stage 3: add block offsets; write row_ptr[N]
__global__ void scan_add(int* __restrict__ row_ptr, const int* __restrict__ boff) {
    int n = blockIdx.x * 256 + threadIdx.x;
    if (n < N_NODES) row_ptr[n] += boff[blockIdx.x];
    if (n == 0) row_ptr[N_NODES] = boff[SCAN_NBLK];
}

// fill CSR position arrays: srcCSR/dstCSR (pos-indexed), pose (edge->pos)
__global__ void fill_kernel(const int* __restrict__ src0, const int* __restrict__ dst0,
                            const int* __restrict__ row_ptr, int* __restrict__ fillc,
                            int* __restrict__ srcCSR, int* __restrict__ dstCSR,
                            int* __restrict__ pose) {
    int e = blockIdx.x * 256 + threadIdx.x;
    if (e < N_EDGES) {
        int d = dst0[e];
        int p = atomicAdd(&fillc[d], 1);
        int pos = row_ptr[d] + p;
        srcCSR[pos] = src0[e];
        dstCSR[pos] = d;
        pose[e] = pos;
    }
}

// ---------------- weight prep ----------------
__global__ void transpose_bf(const float* __restrict__ in, unsigned short* __restrict__ out,
                             int K, int Nn, size_t in_bs, size_t out_bs) {
    in += blockIdx.z * in_bs;
    out += blockIdx.z * out_bs;
    __shared__ float sh[32][33];
    int tx = threadIdx.x, ty = threadIdx.y;
    int kb = blockIdx.y * 32, nb = blockIdx.x * 32;
    #pragma unroll
    for (int i = 0; i < 32; i += 8)
        sh[ty + i][tx] = in[(size_t)(kb + ty + i) * Nn + nb + tx];
    __syncthreads();
    #pragma unroll
    for (int i = 0; i < 32; i += 8)
        out[(size_t)(nb + ty + i) * K + kb + tx] = f2b(sh[tx][ty + i]);
}

// gw2t[l][d][h*256+k] = gat_w[l][k][h*256+d] * 0.25 (head-mean folded in)
__global__ void gat_w_prep(const float* __restrict__ in, unsigned short* __restrict__ out) {
    int z = blockIdx.z, l = z >> 2, h = z & 3;
    __shared__ float sh[32][33];
    int tx = threadIdx.x, ty = threadIdx.y;
    int kb = blockIdx.y * 32, db = blockIdx.x * 32;
    const float* src = in + (size_t)l * HDIM * NH + (size_t)h * HDIM;
    unsigned short* dst = out + (size_t)l * HDIM * NH + (size_t)h * HDIM;
    #pragma unroll
    for (int i = 0; i < 32; i += 8)
        sh[ty + i][tx] = src[(size_t)(kb + ty + i) * NH + db + tx];
    __syncthreads();
    #pragma unroll
    for (int i = 0; i < 32; i += 8)
        dst[(size_t)(db + ty + i) * NH + kb + tx] = f2b(0.25f * sh[tx][ty + i]);
}

// ws_s[l*4+h][k] = sum_d gat_w[l][k][h*256+d] * att_src[l][h][d]; same for dst
__global__ void ws_prep(const float* __restrict__ gat_w, const float* __restrict__ att_src,
                        const float* __restrict__ att_dst,
                        float* __restrict__ ws_s, float* __restrict__ ws_d) {
    int l = blockIdx.x >> 2, h = blockIdx.x & 3;
    int k = threadIdx.x;
    const float* wrow = gat_w + (size_t)l * HDIM * NH + (size_t)k * NH + h * HDIM;
    const float* as = att_src + (size_t)l * NH + h * HDIM;
    const float* ad = att_dst + (size_t)l * NH + h * HDIM;
    float s1 = 0.f, s2 = 0.f;
    for (int d = 0; d < HDIM; d += 4) {
        float4 w4 = *(const float4*)(wrow + d);
        float4 a4 = *(const float4*)(as + d);
        float4 b4 = *(const float4*)(ad + d);
        s1 += w4.x * a4.x + w4.y * a4.y + w4.z * a4.z + w4.w * a4.w;
        s2 += w4.x * b4.x + w4.y * b4.y + w4.z * b4.z + w4.w * b4.w;
    }
    ws_s[(size_t)blockIdx.x * HDIM + k] = s1;
    ws_d[(size_t)blockIdx.x * HDIM + k] = s2;
}

__global__ void conv_bf(const float* __restrict__ in, unsigned short* __restrict__ out) {
    int i = blockIdx.x * 256 + threadIdx.x;
    float4 v = ((const float4*)in)[i];
    ushort4 o;
    o.x = f2b(v.x); o.y = f2b(v.y); o.z = f2b(v.z); o.w = f2b(v.w);
    ((ushort4*)out)[i] = o;
}

// ---------------- bf16 MFMA GEMM ----------------
template <bool RELU, bool BIAS>
__global__ __launch_bounds__(256) void gemm_bf16(
    const unsigned short* __restrict__ A, const unsigned short* __restrict__ Bt,
    const float* __restrict__ bias, unsigned short* __restrict__ C,
    int M, int Ntot, int K)
{
    __shared__ char lds[32768];
    unsigned short* As = (unsigned short*)lds;
    unsigned short* Bs = (unsigned short*)(lds + 8192);
    unsigned short* Cs = (unsigned short*)lds;

    int tid = threadIdx.x;
    int lane = tid & 63;
    int wid = tid >> 6;
    int row0 = blockIdx.y * 128;
    int col0 = blockIdx.x * 128;
    int wm = (wid >> 1) * 64;
    int wn = (wid & 1) * 64;
    int lm = lane & 15;
    int q8 = (lane >> 4) * 8;
    int q4 = (lane >> 4) * 4;

    floatx4 acc[4][4];
    #pragma unroll
    for (int i = 0; i < 4; i++)
        #pragma unroll
        for (int j = 0; j < 4; j++)
            acc[i][j] = (floatx4)(0.f);

    for (int k0 = 0; k0 < K; k0 += 32) {
        #pragma unroll
        for (int r = 0; r < 2; r++) {
            int chunk = tid + r * 256;
            int arow = chunk >> 2;
            int acol = (chunk & 3) * 8;
            int garow = row0 + arow; if (garow > M - 1) garow = M - 1;
            __builtin_amdgcn_global_load_lds(
                (__attribute__((address_space(1))) const void*)(A + (size_t)garow * K + k0 + acol),
                (__attribute__((address_space(3))) void*)(As + chunk * 8), 16, 0, 0);
            __builtin_amdgcn_global_load_lds(
                (__attribute__((address_space(1))) const void*)(Bt + (size_t)(col0 + arow) * K + k0 + acol),
                (__attribute__((address_space(3))) void*)(Bs + chunk * 8), 16, 0, 0);
        }
        __syncthreads();
        short8 af[4], bf[4];
        #pragma unroll
        for (int i = 0; i < 4; i++)
            af[i] = *(const short8*)(As + (wm + i * 16 + lm) * 32 + q8);
        #pragma unroll
        for (int j = 0; j < 4; j++)
            bf[j] = *(const short8*)(Bs + (wn + j * 16 + lm) * 32 + q8);
        #pragma unroll
        for (int i = 0; i < 4; i++)
            #pragma unroll
            for (int j = 0; j < 4; j++)
                acc[i][j] = __builtin_amdgcn_mfma_f32_16x16x32_bf16(af[i], bf[j], acc[i][j], 0, 0, 0);
        __syncthreads();
    }

    #pragma unroll
    for (int i = 0; i < 4; i++) {
        #pragma unroll
        for (int j = 0; j < 4; j++) {
            int cl = wn + j * 16 + lm;
            float bv = BIAS ? bias[col0 + cl] : 0.f;
            #pragma unroll
            for (int reg = 0; reg < 4; reg++) {
                int rl = wm + i * 16 + q4 + reg;
                float v = acc[i][j][reg];
                if (BIAS) v += bv;
                if (RELU) v = fmaxf(v, 0.f);
                Cs[rl * 128 + cl] = f2b(v);
            }
        }
    }
    __syncthreads();
    int row = tid >> 1;
    int ce = (tid & 1) * 64;
    if (row0 + row < M) {
        #pragma unroll
        for (int u = 0; u < 8; u++) {
            int4 v = *(const int4*)(Cs + row * 128 + ce + u * 8);
            *(int4*)(C + (size_t)(row0 + row) * Ntot + col0 + ce + u * 8) = v;
        }
    }
}

// ---------------- per-layer small precompute ----------------
__global__ void layer_prep3(const float* __restrict__ edge_enc_w, const float* __restrict__ edge_enc_b,
                            const float* __restrict__ lin_edge_w, const float* __restrict__ att_edge,
                            float* __restrict__ wmean3, float* __restrict__ scal3)
{
    int l = blockIdx.x;
    const float* eew = edge_enc_w + (size_t)l * EDIM * HDIM;
    const float* eeb = edge_enc_b + (size_t)l * HDIM;
    const float* lew = lin_edge_w + (size_t)l * NH;
    const float* ae  = att_edge + (size_t)l * NH;
    float* wm = wmean3 + l * 64;
    float* sc = scal3 + l * 8;
    int tid = threadIdx.x;
    if (tid < 64) {
        float s = 0.f;
        for (int d = 0; d < HDIM; d++) s += eew[tid * HDIM + d];
        wm[tid] = s * (1.f / HDIM);
    } else if (tid < 68) {
        int h = tid - 64;
        float s = 0.f;
        for (int d = 0; d < HDIM; d++) s += lew[h * HDIM + d] * ae[h * HDIM + d];
        sc[h] = s;
    } else if (tid == 68) {
        float s = 0.f;
        for (int d = 0; d < HDIM; d++) s += eeb[d];
        sc[4] = s * (1.f / HDIM);
    }
}

// ew for all 3 layers, scattered into CSR position order via pose[e]
__global__ __launch_bounds__(256) void edge_weights_all(const float* __restrict__ edge_attr,
                                                        const float* __restrict__ wmean3,
                                                        const float* __restrict__ scal3,
                                                        const int* __restrict__ pose,
                                                        float* __restrict__ ewCSR3)
{
    int e = blockIdx.x * 4 + (threadIdx.x >> 6);
    int lane = threadIdx.x & 63;
    float a = edge_attr[(size_t)e * EDIM + lane];
    float v0 = a * wmean3[lane];
    float v1 = a * wmean3[64 + lane];
    float v2 = a * wmean3[128 + lane];
    #pragma unroll
    for (int off = 32; off > 0; off >>= 1) {
        v0 += __shfl_down(v0, off, 64);
        v1 += __shfl_down(v1, off, 64);
        v2 += __shfl_down(v2, off, 64);
    }
    if (lane == 0) {
        int pos = pose[e];
        ewCSR3[pos] = v0 + scal3[4];
        ewCSR3[N_EDGES + pos] = v1 + scal3[12];
        ewCSR3[2 * N_EDGES + pos] = v2 + scal3[20];
    }
}

__global__ void loop_weights_all(const float* __restrict__ ewCSR3, const int* __restrict__ row_ptr,
                                 float* __restrict__ loopw3)
{
    int n = blockIdx.x * 256 + threadIdx.x;
    if (n >= N_NODES) return;
    int r0 = row_ptr[n], r1 = row_ptr[n + 1];
    float s0 = 0.f, s1 = 0.f, s2 = 0.f;
    for (int i = r0; i < r1; i++) {
        s0 += ewCSR3[i]; s1 += ewCSR3[N_EDGES + i]; s2 += ewCSR3[2 * N_EDGES + i];
    }
    float inv = 1.f / fmaxf((float)(r1 - r0), 1.f);
    loopw3[n] = s0 * inv;
    loopw3[N_NODES + n] = s1 * inv;
    loopw3[2 * N_NODES + n] = s2 * inv;
}

// a_s/a_d from x: wave per node, 4 nodes/block
__global__ __launch_bounds__(256) void attn_x(const unsigned short* __restrict__ x_bf,
                                              const float* __restrict__ ws_s,
                                              const float* __restrict__ ws_d,
                                              float* __restrict__ a_s,
                                              float* __restrict__ a_d)
{
    int wid = threadIdx.x >> 6, lane = threadIdx.x & 63;
    int n = blockIdx.x * 4 + wid;
    ushort4 xv = *(const ushort4*)(x_bf + (size_t)n * HDIM + lane * 4);
    float x0 = b2f(xv.x), x1 = b2f(xv.y), x2 = b2f(xv.z), x3 = b2f(xv.w);
    float ss[4], sd[4];
    #pragma unroll
    for (int h = 0; h < 4; h++) {
        float4 s4 = *(const float4*)(ws_s + h * HDIM + lane * 4);
        float4 d4 = *(const float4*)(ws_d + h * HDIM + lane * 4);
        ss[h] = x0 * s4.x + x1 * s4.y + x2 * s4.z + x3 * s4.w;
        sd[h] = x0 * d4.x + x1 * d4.y + x2 * d4.z + x3 * d4.w;
    }
    #pragma unroll
    for (int off = 32; off > 0; off >>= 1)
        #pragma unroll
        for (int h = 0; h < 4; h++) {
            ss[h] += __shfl_xor(ss[h], off, 64);
            sd[h] += __shfl_xor(sd[h], off, 64);
        }
    if (lane == 0) {
        *(float4*)(a_s + n * 4) = make_float4(ss[0], ss[1], ss[2], ss[3]);
        *(float4*)(a_d + n * 4) = make_float4(sd[0], sd[1], sd[2], sd[3]);
    }
}

// z[pos][h] = leaky_relu(a_s[src] + a_d[dst] + c[h]*ew), CSR order, coalesced
__global__ __launch_bounds__(256) void edge_logits(const int* __restrict__ srcCSR,
                                                   const int* __restrict__ dstCSR,
                                                   const float* __restrict__ ewCSR,
                                                   const float* __restrict__ a_s,
                                                   const float* __restrict__ a_d,
                                                   const float* __restrict__ scal,
                                                   float* __restrict__ zCSR)
{
    int pos = blockIdx.x * 256 + threadIdx.x;
    if (pos >= N_EDGES) return;
    int sn = srcCSR[pos], dn = dstCSR[pos];
    float w = ewCSR[pos];
    float4 c4 = *(const float4*)scal;
    float4 zs = *(const float4*)(a_s + sn * 4);
    float4 zd = *(const float4*)(a_d + dn * 4);
    float4 z;
    z.x = zs.x + zd.x + c4.x * w; z.x = z.x > 0.f ? z.x : 0.2f * z.x;
    z.y = zs.y + zd.y + c4.y * w; z.y = z.y > 0.f ? z.y : 0.2f * z.y;
    z.z = zs.z + zd.z + c4.z * w; z.z = z.z > 0.f ? z.z : 0.2f * z.z;
    z.w = zs.w + zd.w + c4.w * w; z.w = z.w > 0.f ? z.w : 0.2f * z.w;
    ((float4*)zCSR)[pos] = z;
}

// Wave-per-node softmax + aggregate. 4 nodes/block, no __syncthreads.
__global__ __launch_bounds__(256) void gat_agg_wave(
    const unsigned short* __restrict__ x_bf, const float* __restrict__ a_s,
    const float* __restrict__ a_d, const float* __restrict__ loopw,
    const float* __restrict__ scal, const int* __restrict__ row_ptr,
    const int* __restrict__ srcCSR, const float* __restrict__ zCSR,
    unsigned short* __restrict__ agg)
{
    int wid = threadIdx.x >> 6, lane = threadIdx.x & 63;
    int n = blockIdx.x * 4 + wid;
    int r0 = row_ptr[n];
    int deg = row_ptr[n + 1] - r0;
    int cnt = deg + 1;

    float4 c4 = *(const float4*)scal;
    float4 as = *(const float4*)(a_s + n * 4);
    float4 ad = *(const float4*)(a_d + n * 4);
    float lw = loopw[n];
    float4 zself;
    zself.x = as.x + ad.x + c4.x * lw; zself.x = zself.x > 0.f ? zself.x : 0.2f * zself.x;
    zself.y = as.y + ad.y + c4.y * lw; zself.y = zself.y > 0.f ? zself.y : 0.2f * zself.y;
    zself.z = as.z + ad.z + c4.z * lw; zself.z = zself.z > 0.f ? zself.z : 0.2f * zself.z;
    zself.w = as.w + ad.w + c4.w * lw; zself.w = zself.w > 0.f ? zself.w : 0.2f * zself.w;

    auto load_z = [&](int c0) -> float4 {
        int idx = c0 + lane;
        if (idx < deg) return ((const float4*)zCSR)[r0 + idx];
        if (idx == deg) return zself;
        return make_float4(-1e30f, -1e30f, -1e30f, -1e30f);
    };
    auto load_s = [&](int c0) -> int {
        int idx = c0 + lane;
        return (idx < deg) ? srcCSR[r0 + idx] : n;
    };

    float4 zc0 = load_z(0);
    int sv0 = load_s(0);

    // stats pass 1: max
    float m0 = zc0.x, m1 = zc0.y, m2 = zc0.z, m3 = zc0.w;
    for (int c0 = 64; c0 < cnt; c0 += 64) {
        float4 z = load_z(c0);
        m0 = fmaxf(m0, z.x); m1 = fmaxf(m1, z.y);
        m2 = fmaxf(m2, z.z); m3 = fmaxf(m3, z.w);
    }
    #pragma unroll
    for (int off = 32; off > 0; off >>= 1) {
        m0 = fmaxf(m0, __shfl_xor(m0, off, 64));
        m1 = fmaxf(m1, __shfl_xor(m1, off, 64));
        m2 = fmaxf(m2, __shfl_xor(m2, off, 64));
        m3 = fmaxf(m3, __shfl_xor(m3, off, 64));
    }
    // stats pass 2: sum exp
    float s0 = __expf(zc0.x - m0), s1 = __expf(zc0.y - m1);
    float s2 = __expf(zc0.z - m2), s3 = __expf(zc0.w - m3);
    for (int c0 = 64; c0 < cnt; c0 += 64) {
        float4 z = load_z(c0);
        s0 += __expf(z.x - m0); s1 += __expf(z.y - m1);
        s2 += __expf(z.z - m2); s3 += __expf(z.w - m3);
    }
    #pragma unroll
    for (int off = 32; off > 0; off >>= 1) {
        s0 += __shfl_xor(s0, off, 64);
        s1 += __shfl_xor(s1, off, 64);
        s2 += __shfl_xor(s2, off, 64);
        s3 += __shfl_xor(s3, off, 64);
    }
    float i0 = 1.f / s0, i1 = 1.f / s1, i2 = 1.f / s2, i3 = 1.f / s3;

    // aggregation
    float acc[4][4] = {};
    const unsigned short* xw = x_bf + (size_t)lane * 4;
    for (int c0 = 0; c0 < cnt; c0 += 64) {
        float4 z = (c0 == 0) ? zc0 : load_z(c0);
        int sv = (c0 == 0) ? sv0 : load_s(c0);
        int mc = min(64, cnt - c0);
        int j = 0;
        for (; j + 1 < mc; j += 2) {
            int sA = __builtin_amdgcn_readfirstlane(__shfl(sv, j, 64));
            int sB = __builtin_amdgcn_readfirstlane(__shfl(sv, j + 1, 64));
            uint2 uA = *(const uint2*)(xw + (size_t)sA * HDIM);
            uint2 uB = *(const uint2*)(xw + (size_t)sB * HDIM);
            float aA0 = __expf(__shfl(z.x, j, 64) - m0) * i0;
            float aA1 = __expf(__shfl(z.y, j, 64) - m1) * i1;
            float aA2 = __expf(__shfl(z.z, j, 64) - m2) * i2;
            float aA3 = __expf(__shfl(z.w, j, 64) - m3) * i3;
            float aB0 = __expf(__shfl(z.x, j + 1, 64) - m0) * i0;
            float aB1 = __expf(__shfl(z.y, j + 1, 64) - m1) * i1;
            float aB2 = __expf(__shfl(z.z, j + 1, 64) - m2) * i2;
            float aB3 = __expf(__shfl(z.w, j + 1, 64) - m3) * i3;
            float xa0 = b2f_lo(uA.x), xa1 = b2f_hi(uA.x), xa2 = b2f_lo(uA.y), xa3 = b2f_hi(uA.y);
            float xb0 = b2f_lo(uB.x), xb1 = b2f_hi(uB.x), xb2 = b2f_lo(uB.y), xb3 = b2f_hi(uB.y);
            acc[0][0] += aA0 * xa0 + aB0 * xb0; acc[0][1] += aA0 * xa1 + aB0 * xb1;
            acc[0][2] += aA0 * xa2 + aB0 * xb2; acc[0][3] += aA0 * xa3 + aB0 * xb3;
            acc[1][0] += aA1 * xa0 + aB1 * xb0; acc[1][1] += aA1 * xa1 + aB1 * xb1;
            acc[1][2] += aA1 * xa2 + aB1 * xb2; acc[1][3] += aA1 * xa3 + aB1 * xb3;
            acc[2][0] += aA2 * xa0 + aB2 * xb0; acc[2][1] += aA2 * xa1 + aB2 * xb1;
            acc[2][2] += aA2 * xa2 + aB2 * xb2; acc[2][3] += aA2 * xa3 + aB2 * xb3;
            acc[3][0] += aA3 * xa0 + aB3 * xb0; acc[3][1] += aA3 * xa1 + aB3 * xb1;
            acc[3][2] += aA3 * xa2 + aB3 * xb2; acc[3][3] += aA3 * xa3 + aB3 * xb3;
        }
        if (j < mc) {
            int sA = __builtin_amdgcn_readfirstlane(__shfl(sv, j, 64));
            uint2 uA = *(const uint2*)(xw + (size_t)sA * HDIM);
            float aA0 = __expf(__shfl(z.x, j, 64) - m0) * i0;
            float aA1 = __expf(__shfl(z.y, j, 64) - m1) * i1;
            float aA2 = __expf(__shfl(z.z, j, 64) - m2) * i2;
            float aA3 = __expf(__shfl(z.w, j, 64) - m3) * i3;
            float xa0 = b2f_lo(uA.x), xa1 = b2f_hi(uA.x), xa2 = b2f_lo(uA.y), xa3 = b2f_hi(uA.y);
            acc[0][0] += aA0 * xa0; acc[0][1] += aA0 * xa1; acc[0][2] += aA0 * xa2; acc[0][3] += aA0 * xa3;
            acc[1][0] += aA1 * xa0; acc[1][1] += aA1 * xa1; acc[1][2] += aA1 * xa2; acc[1][3] += aA1 * xa3;
            acc[2][0] += aA2 * xa0; acc[2][1] += aA2 * xa1; acc[2][2] += aA2 * xa2; acc[2][3] += aA2 * xa3;
            acc[3][0] += aA3 * xa0; acc[3][1] += aA3 * xa1; acc[3][2] += aA3 * xa2; acc[3][3] += aA3 * xa3;
        }
    }

    unsigned short* ag = agg + (size_t)n * NH + lane * 4;
    #pragma unroll
    for (int h = 0; h < 4; h++) {
        ushort4 o;
        o.x = f2b(acc[h][0]); o.y = f2b(acc[h][1]);
        o.z = f2b(acc[h][2]); o.w = f2b(acc[h][3]);
        *(ushort4*)(ag + h * 256) = o;
    }
}

// LN(y) + residual ReLU, in-place x. One wave per node.
__global__ __launch_bounds__(256) void ln_residual(const unsigned short* __restrict__ y_bf,
                                                   const float* __restrict__ ln_g,
                                                   const float* __restrict__ ln_b,
                                                   unsigned short* __restrict__ x_bf)
{
    int n = blockIdx.x * 4 + (threadIdx.x >> 6);
    int lane = threadIdx.x & 63;
    ushort4 yv = *(const ushort4*)(y_bf + (size_t)n * HDIM + lane * 4);
    float y0 = b2f(yv.x), y1 = b2f(yv.y), y2 = b2f(yv.z), y3 = b2f(yv.w);
    float s1 = y0 + y1 + y2 + y3;
    float s2 = y0 * y0 + y1 * y1 + y2 * y2 + y3 * y3;
    #pragma unroll
    for (int off = 32; off > 0; off >>= 1) {
        s1 += __shfl_xor(s1, off, 64);
        s2 += __shfl_xor(s2, off, 64);
    }
    float mu = s1 * (1.f / HDIM);
    float var = s2 * (1.f / HDIM) - mu * mu;
    float rsig = rsqrtf(var + 1e-5f);
    float4 g = *(const float4*)(ln_g + lane * 4);
    float4 b = *(const float4*)(ln_b + lane * 4);
    ushort4 xv = *(const ushort4*)(x_bf + (size_t)n * HDIM + lane * 4);
    ushort4 o;
    o.x = f2b(fmaxf(b2f(xv.x) + g.x * (y0 - mu) * rsig + b.x, 0.f));
    o.y = f2b(fmaxf(b2f(xv.y) + g.y * (y1 - mu) * rsig + b.y, 0.f));
    o.z = f2b(fmaxf(b2f(xv.z) + g.z * (y2 - mu) * rsig + b.z, 0.f));
    o.w = f2b(fmaxf(b2f(xv.w) + g.w * (y3 - mu) * rsig + b.w, 0.f));
    *(ushort4*)(x_bf + (size_t)n * HDIM + lane * 4) = o;
}

__global__ __launch_bounds__(256) void head2_kernel(const unsigned short* __restrict__ hmid,
                                                    const float* __restrict__ w2,
                                                    const float* __restrict__ b2,
                                                    float* __restrict__ out)
{
    int gw = blockIdx.x * 4 + (threadIdx.x >> 6);
    int lane = threadIdx.x & 63;
    int n = gw >> 2;
    int k = gw & 3;
    const unsigned short* hr = hmid + (size_t)n * 512 + k * 128;
    const float* wr = w2 + k * 128;
    float s = b2f(hr[lane]) * wr[lane] + b2f(hr[lane + 64]) * wr[lane + 64];
    s = wave_reduce_sum(s);
    if (lane == 0) {
        s += b2[k];
        if (k == 0 || k == 3) s = 1.f / (1.f + __expf(-s));
        out[(size_t)k * N_NODES + n] = s;
    }
}

__global__ void copy_emb(const unsigned short* __restrict__ x_bf, float* __restrict__ out) {
    int i = blockIdx.x * 256 + threadIdx.x;
    ushort4 v = ((const ushort4*)x_bf)[i];
    float4 o = make_float4(b2f(v.x), b2f(v.y), b2f(v.z), b2f(v.w));
    ((float4*)out)[i] = o;
}

extern "C" void kernel_launch(void* const* d_in, const int* in_sizes, int n_in,
                              void* d_out, int out_size, void* d_ws, size_t ws_size,
                              hipStream_t stream) {
    const float* node_features = (const float*)d_in[0];
    const float* edge_attr     = (const float*)d_in[1];
    const float* enc_w         = (const float*)d_in[2];
    const float* enc_b         = (const float*)d_in[3];
    const float* edge_enc_w    = (const float*)d_in[4];
    const float* edge_enc_b    = (const float*)d_in[5];
    const float* gat_w         = (const float*)d_in[6];
    const float* att_src       = (const float*)d_in[7];
    const float* att_dst       = (const float*)d_in[8];
    const float* att_edge      = (const float*)d_in[9];
    const float* lin_edge_w    = (const float*)d_in[10];
    const float* gat_b         = (const float*)d_in[11];
    const float* ln_g          = (const float*)d_in[12];
    const float* ln_b          = (const float*)d_in[13];
    const float* head_w1       = (const float*)d_in[14];
    const float* head_b1       = (const float*)d_in[15];
    const float* head_w2       = (const float*)d_in[16];
    const float* head_b2       = (const float*)d_in[17];
    const int*   edge_index    = (const int*)d_in[18];
    const int* src0 = edge_index;
    const int* dst0 = edge_index + N_EDGES;
    float* out = (float*)d_out;

    char* cur = (char*)d_ws;
    auto alloc = [&](size_t bytes) { char* p = cur; cur += (bytes + 255) & ~(size_t)255; return p; };
    unsigned short* x_bf   = (unsigned short*)alloc((size_t)N_NODES * HDIM * 2);
    unsigned short* agg    = (unsigned short*)alloc((size_t)N_NODES * NH * 2);   // also hmid
    unsigned short* y_bf   = (unsigned short*)alloc((size_t)N_NODES * HDIM * 2);
    unsigned short* nf_bf  = (unsigned short*)alloc((size_t)N_NODES * NDIM * 2);
    unsigned short* enc_wt = (unsigned short*)alloc((size_t)HDIM * NDIM * 2);
    unsigned short* gw2t   = (unsigned short*)alloc((size_t)NLAYERS * NH * HDIM * 2);
    unsigned short* hw1t   = (unsigned short*)alloc((size_t)512 * HDIM * 2);
    float* ws_s   = (float*)alloc((size_t)NLAYERS * 4 * HDIM * 4);
    float* ws_d   = (float*)alloc((size_t)NLAYERS * 4 * HDIM * 4);
    float* a_s    = (float*)alloc((size_t)N_NODES * 4 * 4);
    float* a_d    = (float*)alloc((size_t)N_NODES * 4 * 4);
    float* ewCSR3 = (float*)alloc((size_t)3 * N_EDGES * 4);
    float* loopw3 = (float*)alloc((size_t)3 * N_NODES * 4);
    float* zCSR   = (float*)alloc((size_t)N_EDGES * 4 * 4);
    float* wmean3 = (float*)alloc(192 * 4);
    float* scal3  = (float*)alloc(24 * 4);
    // cnt+fillc contiguous: single memset must cover both exactly (R2 lesson)
    int* cnt      = (int*)alloc((size_t)2 * N_NODES * 4);
    int* fillc    = cnt + N_NODES;
    int* row_ptr  = (int*)alloc((size_t)(N_NODES + 1) * 4);
    int* bsum     = (int*)alloc((size_t)(SCAN_NBLK + 1) * 4);
    int* boff     = (int*)alloc((size_t)(SCAN_NBLK + 1) * 4);
    int* srcCSR   = (int*)alloc((size_t)N_EDGES * 4);
    int* dstCSR   = (int*)alloc((size_t)N_EDGES * 4);
    int* pose     = (int*)alloc((size_t)N_EDGES * 4);
    unsigned short* hmid = agg;

    hipMemsetAsync(cnt, 0, (size_t)2 * N_NODES * sizeof(int), stream);

    hist_kernel<<<(N_EDGES + 255) / 256, 256, 0, stream>>>(dst0, cnt);
    scan_local<<<SCAN_NBLK, 256, 0, stream>>>(cnt, row_ptr, bsum);
    scan_bsums<<<1, 128, 0, stream>>>(bsum, boff);
    scan_add<<<SCAN_NBLK, 256, 0, stream>>>(row_ptr, boff);
    fill_kernel<<<(N_EDGES + 255) / 256, 256, 0, stream>>>(src0, dst0, row_ptr, fillc,
                                                           srcCSR, dstCSR, pose);

    conv_bf<<<(N_NODES * NDIM / 4) / 256, 256, 0, stream>>>(node_features, nf_bf);
    transpose_bf<<<dim3(HDIM / 32, NDIM / 32, 1), dim3(32, 8), 0, stream>>>(
        enc_w, enc_wt, NDIM, HDIM, 0, 0);
    gat_w_prep<<<dim3(8, 8, 12), dim3(32, 8), 0, stream>>>(gat_w, gw2t);
    ws_prep<<<12, 256, 0, stream>>>(gat_w, att_src, att_dst, ws_s, ws_d);
    transpose_bf<<<dim3(128 / 32, HDIM / 32, 4), dim3(32, 8), 0, stream>>>(
        head_w1, hw1t, HDIM, 128, (size_t)HDIM * 128, (size_t)128 * HDIM);

    layer_prep3<<<3, 128, 0, stream>>>(edge_enc_w, edge_enc_b, lin_edge_w, att_edge, wmean3, scal3);
    edge_weights_all<<<N_EDGES / 4, 256, 0, stream>>>(edge_attr, wmean3, scal3, pose, ewCSR3);
    loop_weights_all<<<(N_NODES + 255) / 256, 256, 0, stream>>>(ewCSR3, row_ptr, loopw3);

    gemm_bf16<true, true><<<dim3(HDIM / 128, (N_NODES + 127) / 128), 256, 0, stream>>>(
        nf_bf, enc_wt, enc_b, x_bf, N_NODES, HDIM, NDIM);

    for (int l = 0; l < NLAYERS; l++) {
        attn_x<<<N_NODES / 4, 256, 0, stream>>>(x_bf, ws_s + (size_t)l * 4 * HDIM,
                                                ws_d + (size_t)l * 4 * HDIM, a_s, a_d);
        edge_logits<<<(N_EDGES + 255) / 256, 256, 0, stream>>>(
            srcCSR, dstCSR, ewCSR3 + (size_t)l * N_EDGES, a_s, a_d, scal3 + l * 8, zCSR);
        gat_agg_wave<<<N_NODES / 4, 256, 0, stream>>>(
            x_bf, a_s, a_d, loopw3 + (size_t)l * N_NODES, scal3 + l * 8,
            row_ptr, srcCSR, zCSR, agg);
        gemm_bf16<false, true><<<dim3(HDIM / 128, (N_NODES + 127) / 128), 256, 0, stream>>>(
            agg, gw2t + (size_t)l * NH * HDIM, gat_b + (size_t)l * HDIM, y_bf,
            N_NODES, HDIM, NH);
        ln_residual<<<N_NODES / 4, 256, 0, stream>>>(y_bf, ln_g + (size_t)l * HDIM,
                                                     ln_b + (size_t)l * HDIM, x_bf);
    }

    gemm_bf16<true, true><<<dim3(512 / 128, (N_NODES + 127) / 128), 256, 0, stream>>>(
        x_bf, hw1t, head_b1, hmid, N_NODES, 512, HDIM);
    head2_kernel<<<N_NODES, 256, 0, stream>>>(hmid, head_w2, head_b2, out);

    copy_emb<<<(N_NODES * HDIM / 4) / 256, 256, 0, stream>>>(x_bf, out + 4 * N_NODES);
}

// Round 9
// 527.018 us; speedup vs baseline: 1.4096x; 1.0409x over previous
//
#include <hip/hip_runtime.h>
#include <math.h>

#define N_NODES 20000
#define N_EDGES 200000
#define NDIM 128
#define EDIM 64
#define HDIM 256
#define HEADS 4
#define NH 1024
#define NLAYERS 3
#define SCAN_NBLK ((N_NODES + 255) / 256)   // 79

typedef __attribute__((ext_vector_type(8))) short short8;
typedef __attribute__((ext_vector_type(4))) float floatx4;

__device__ __forceinline__ float b2f(unsigned short u) {
    union { unsigned u; float f; } c; c.u = ((unsigned)u) << 16; return c.f;
}
__device__ __forceinline__ float b2f_lo(unsigned u) {
    union { unsigned u; float f; } c; c.u = u << 16; return c.f;
}
__device__ __forceinline__ float b2f_hi(unsigned u) {
    union { unsigned u; float f; } c; c.u = u & 0xffff0000u; return c.f;
}
__device__ __forceinline__ unsigned short f2b(float f) {
    union { float f; unsigned u; } c; c.f = f;
    unsigned u = c.u;
    return (unsigned short)((u + 0x7FFFu + ((u >> 16) & 1u)) >> 16);
}

__device__ __forceinline__ float wave_reduce_sum(float v) {
    #pragma unroll
    for (int off = 32; off > 0; off >>= 1) v += __shfl_down(v, off, 64);
    return v;
}

// ---------------- CSR build ----------------
__global__ void hist_kernel(const int* __restrict__ dst0, int* __restrict__ cnt) {
    int e = blockIdx.x * 256 + threadIdx.x;
    if (e < N_EDGES) atomicAdd(&cnt[dst0[e]], 1);
}

// parallel scan, stage 1: per-block exclusive scan + block totals
__global__ void scan_local(const int* __restrict__ cnt, int* __restrict__ row_ptr,
                           int* __restrict__ bsum) {
    __shared__ int wsum[4];
    int tid = threadIdx.x, lane = tid & 63, wid = tid >> 6;
    int n = blockIdx.x * 256 + tid;
    int v = (n < N_NODES) ? cnt[n] : 0;
    int s = v;
    #pragma unroll
    for (int off = 1; off < 64; off <<= 1) {
        int t = __shfl_up(s, off, 64);
        if (lane >= off) s += t;
    }
    if (lane == 63) wsum[wid] = s;
    __syncthreads();
    int woff = 0;
    #pragma unroll
    for (int w = 0; w < 4; w++) if (w < wid) woff += wsum[w];
    if (n < N_NODES) row_ptr[n] = woff + s - v;   // local exclusive
    if (tid == 255) bsum[blockIdx.x] = woff + s;
}

// stage 2: scan the (79) block totals in one block
__global__ void scan_bsums(int* __restrict__ bsum, int* __restrict__ boff) {
    __shared__ int wsum[2];
    int tid = threadIdx.x, lane = tid & 63, wid = tid >> 6;  // 128 threads
    int v = (tid < SCAN_NBLK) ? bsum[tid] : 0;
    int s = v;
    #pragma unroll
    for (int off = 1; off < 64; off <<= 1) {
        int t = __shfl_up(s, off, 64);
        if (lane >= off) s += t;
    }
    if (lane == 63) wsum[wid] = s;
    __syncthreads();
    int woff = (wid == 1) ? wsum[0] : 0;
    if (tid < SCAN_NBLK) boff[tid] = woff + s - v;   // exclusive
    if (tid == SCAN_NBLK - 1) boff[SCAN_NBLK] = woff + s;  // total
}

// stage 3: add block offsets; write row_ptr[N]
__global__ void scan_add(int* __restrict__ row_ptr, const int* __restrict__ boff) {
    int n = blockIdx.x * 256 + threadIdx.x;
    if (n < N_NODES) row_ptr[n] += boff[blockIdx.x];
    if (n == 0) row_ptr[N_NODES] = boff[SCAN_NBLK];
}

// fill CSR position arrays: srcCSR/dstCSR (pos-indexed), pose (edge->pos)
__global__ void fill_kernel(const int* __restrict__ src0, const int* __restrict__ dst0,
                            const int* __restrict__ row_ptr, int* __restrict__ fillc,
                            int* __restrict__ srcCSR, int* __restrict__ dstCSR,
                            int* __restrict__ pose) {
    int e = blockIdx.x * 256 + threadIdx.x;
    if (e < N_EDGES) {
        int d = dst0[e];
        int p = atomicAdd(&fillc[d], 1);
        int pos = row_ptr[d] + p;
        srcCSR[pos] = src0[e];
        dstCSR[pos] = d;
        pose[e] = pos;
    }
}

// ---------------- weight prep ----------------
__global__ void transpose_bf(const float* __restrict__ in, unsigned short* __restrict__ out,
                             int K, int Nn, size_t in_bs, size_t out_bs) {
    in += blockIdx.z * in_bs;
    out += blockIdx.z * out_bs;
    __shared__ float sh[32][33];
    int tx = threadIdx.x, ty = threadIdx.y;
    int kb = blockIdx.y * 32, nb = blockIdx.x * 32;
    #pragma unroll
    for (int i = 0; i < 32; i += 8)
        sh[ty + i][tx] = in[(size_t)(kb + ty + i) * Nn + nb + tx];
    __syncthreads();
    #pragma unroll
    for (int i = 0; i < 32; i += 8)
        out[(size_t)(nb + ty + i) * K + kb + tx] = f2b(sh[tx][ty + i]);
}

// gw2t[l][d][h*256+k] = gat_w[l][k][h*256+d] * 0.25 (head-mean folded in)
__global__ void gat_w_prep(const float* __restrict__ in, unsigned short* __restrict__ out) {
    int z = blockIdx.z, l = z >> 2, h = z & 3;
    __shared__ float sh[32][33];
    int tx = threadIdx.x, ty = threadIdx.y;
    int kb = blockIdx.y * 32, db = blockIdx.x * 32;
    const float* src = in + (size_t)l * HDIM * NH + (size_t)h * HDIM;
    unsigned short* dst = out + (size_t)l * HDIM * NH + (size_t)h * HDIM;
    #pragma unroll
    for (int i = 0; i < 32; i += 8)
        sh[ty + i][tx] = src[(size_t)(kb + ty + i) * NH + db + tx];
    __syncthreads();
    #pragma unroll
    for (int i = 0; i < 32; i += 8)
        dst[(size_t)(db + ty + i) * NH + kb + tx] = f2b(0.25f * sh[tx][ty + i]);
}

// ws_s[l*4+h][k] = sum_d gat_w[l][k][h*256+d] * att_src[l][h][d]; same for dst
__global__ void ws_prep(const float* __restrict__ gat_w, const float* __restrict__ att_src,
                        const float* __restrict__ att_dst,
                        float* __restrict__ ws_s, float* __restrict__ ws_d) {
    int l = blockIdx.x >> 2, h = blockIdx.x & 3;
    int k = threadIdx.x;
    const float* wrow = gat_w + (size_t)l * HDIM * NH + (size_t)k * NH + h * HDIM;
    const float* as = att_src + (size_t)l * NH + h * HDIM;
    const float* ad = att_dst + (size_t)l * NH + h * HDIM;
    float s1 = 0.f, s2 = 0.f;
    for (int d = 0; d < HDIM; d += 4) {
        float4 w4 = *(const float4*)(wrow + d);
        float4 a4 = *(const float4*)(as + d);
        float4 b4 = *(const float4*)(ad + d);
        s1 += w4.x * a4.x + w4.y * a4.y + w4.z * a4.z + w4.w * a4.w;
        s2 += w4.x * b4.x + w4.y * b4.y + w4.z * b4.z + w4.w * b4.w;
    }
    ws_s[(size_t)blockIdx.x * HDIM + k] = s1;
    ws_d[(size_t)blockIdx.x * HDIM + k] = s2;
}

__global__ void conv_bf(const float* __restrict__ in, unsigned short* __restrict__ out) {
    int i = blockIdx.x * 256 + threadIdx.x;
    float4 v = ((const float4*)in)[i];
    ushort4 o;
    o.x = f2b(v.x); o.y = f2b(v.y); o.z = f2b(v.z); o.w = f2b(v.w);
    ((ushort4*)out)[i] = o;
}

// ---------------- bf16 MFMA GEMM ----------------
template <bool RELU, bool BIAS>
__global__ __launch_bounds__(256) void gemm_bf16(
    const unsigned short* __restrict__ A, const unsigned short* __restrict__ Bt,
    const float* __restrict__ bias, unsigned short* __restrict__ C,
    int M, int Ntot, int K)
{
    __shared__ char lds[32768];
    unsigned short* As = (unsigned short*)lds;
    unsigned short* Bs = (unsigned short*)(lds + 8192);
    unsigned short* Cs = (unsigned short*)lds;

    int tid = threadIdx.x;
    int lane = tid & 63;
    int wid = tid >> 6;
    int row0 = blockIdx.y * 128;
    int col0 = blockIdx.x * 128;
    int wm = (wid >> 1) * 64;
    int wn = (wid & 1) * 64;
    int lm = lane & 15;
    int q8 = (lane >> 4) * 8;
    int q4 = (lane >> 4) * 4;

    floatx4 acc[4][4];
    #pragma unroll
    for (int i = 0; i < 4; i++)
        #pragma unroll
        for (int j = 0; j < 4; j++)
            acc[i][j] = (floatx4)(0.f);

    for (int k0 = 0; k0 < K; k0 += 32) {
        #pragma unroll
        for (int r = 0; r < 2; r++) {
            int chunk = tid + r * 256;
            int arow = chunk >> 2;
            int acol = (chunk & 3) * 8;
            int garow = row0 + arow; if (garow > M - 1) garow = M - 1;
            __builtin_amdgcn_global_load_lds(
                (__attribute__((address_space(1))) const void*)(A + (size_t)garow * K + k0 + acol),
                (__attribute__((address_space(3))) void*)(As + chunk * 8), 16, 0, 0);
            __builtin_amdgcn_global_load_lds(
                (__attribute__((address_space(1))) const void*)(Bt + (size_t)(col0 + arow) * K + k0 + acol),
                (__attribute__((address_space(3))) void*)(Bs + chunk * 8), 16, 0, 0);
        }
        __syncthreads();
        short8 af[4], bf[4];
        #pragma unroll
        for (int i = 0; i < 4; i++)
            af[i] = *(const short8*)(As + (wm + i * 16 + lm) * 32 + q8);
        #pragma unroll
        for (int j = 0; j < 4; j++)
            bf[j] = *(const short8*)(Bs + (wn + j * 16 + lm) * 32 + q8);
        #pragma unroll
        for (int i = 0; i < 4; i++)
            #pragma unroll
            for (int j = 0; j < 4; j++)
                acc[i][j] = __builtin_amdgcn_mfma_f32_16x16x32_bf16(af[i], bf[j], acc[i][j], 0, 0, 0);
        __syncthreads();
    }

    #pragma unroll
    for (int i = 0; i < 4; i++) {
        #pragma unroll
        for (int j = 0; j < 4; j++) {
            int cl = wn + j * 16 + lm;
            float bv = BIAS ? bias[col0 + cl] : 0.f;
            #pragma unroll
            for (int reg = 0; reg < 4; reg++) {
                int rl = wm + i * 16 + q4 + reg;
                float v = acc[i][j][reg];
                if (BIAS) v += bv;
                if (RELU) v = fmaxf(v, 0.f);
                Cs[rl * 128 + cl] = f2b(v);
            }
        }
    }
    __syncthreads();
    int row = tid >> 1;
    int ce = (tid & 1) * 64;
    if (row0 + row < M) {
        #pragma unroll
        for (int u = 0; u < 8; u++) {
            int4 v = *(const int4*)(Cs + row * 128 + ce + u * 8);
            *(int4*)(C + (size_t)(row0 + row) * Ntot + col0 + ce + u * 8) = v;
        }
    }
}

// ---------------- per-layer small precompute ----------------
__global__ void layer_prep3(const float* __restrict__ edge_enc_w, const float* __restrict__ edge_enc_b,
                            const float* __restrict__ lin_edge_w, const float* __restrict__ att_edge,
                            float* __restrict__ wmean3, float* __restrict__ scal3)
{
    int l = blockIdx.x;
    const float* eew = edge_enc_w + (size_t)l * EDIM * HDIM;
    const float* eeb = edge_enc_b + (size_t)l * HDIM;
    const float* lew = lin_edge_w + (size_t)l * NH;
    const float* ae  = att_edge + (size_t)l * NH;
    float* wm = wmean3 + l * 64;
    float* sc = scal3 + l * 8;
    int tid = threadIdx.x;
    if (tid < 64) {
        float s = 0.f;
        for (int d = 0; d < HDIM; d++) s += eew[tid * HDIM + d];
        wm[tid] = s * (1.f / HDIM);
    } else if (tid < 68) {
        int h = tid - 64;
        float s = 0.f;
        for (int d = 0; d < HDIM; d++) s += lew[h * HDIM + d] * ae[h * HDIM + d];
        sc[h] = s;
    } else if (tid == 68) {
        float s = 0.f;
        for (int d = 0; d < HDIM; d++) s += eeb[d];
        sc[4] = s * (1.f / HDIM);
    }
}

// thread-per-edge: 16 independent float4 loads (full MLP), 3 dots vs uniform
// wmean (scalar loads), ONE 16B scatter-write (ew_l0,ew_l1,ew_l2,0) to CSR pos.
__global__ __launch_bounds__(256) void edge_weights_all(const float* __restrict__ edge_attr,
                                                        const float* __restrict__ wmean3,
                                                        const float* __restrict__ scal3,
                                                        const int* __restrict__ pose,
                                                        float* __restrict__ ewCSR4)
{
    int e = blockIdx.x * 256 + threadIdx.x;
    if (e >= N_EDGES) return;
    const float* row = edge_attr + (size_t)e * EDIM;
    float s0 = 0.f, s1 = 0.f, s2 = 0.f;
    #pragma unroll
    for (int d = 0; d < EDIM; d += 4) {
        float4 a  = *(const float4*)(row + d);
        float4 w0 = *(const float4*)(wmean3 + d);
        float4 w1 = *(const float4*)(wmean3 + 64 + d);
        float4 w2 = *(const float4*)(wmean3 + 128 + d);
        s0 += a.x * w0.x + a.y * w0.y + a.z * w0.z + a.w * w0.w;
        s1 += a.x * w1.x + a.y * w1.y + a.z * w1.z + a.w * w1.w;
        s2 += a.x * w2.x + a.y * w2.y + a.z * w2.z + a.w * w2.w;
    }
    int pos = pose[e];
    *(float4*)(ewCSR4 + (size_t)pos * 4) =
        make_float4(s0 + scal3[4], s1 + scal3[12], s2 + scal3[20], 0.f);
}

__global__ void loop_weights_all(const float* __restrict__ ewCSR4, const int* __restrict__ row_ptr,
                                 float* __restrict__ loopw3)
{
    int n = blockIdx.x * 256 + threadIdx.x;
    if (n >= N_NODES) return;
    int r0 = row_ptr[n], r1 = row_ptr[n + 1];
    float s0 = 0.f, s1 = 0.f, s2 = 0.f;
    for (int i = r0; i < r1; i++) {
        float4 w = *(const float4*)(ewCSR4 + (size_t)i * 4);
        s0 += w.x; s1 += w.y; s2 += w.z;
    }
    float inv = 1.f / fmaxf((float)(r1 - r0), 1.f);
    loopw3[n] = s0 * inv;
    loopw3[N_NODES + n] = s1 * inv;
    loopw3[2 * N_NODES + n] = s2 * inv;
}

// a_s/a_d from x: wave per node, 4 nodes/block
__global__ __launch_bounds__(256) void attn_x(const unsigned short* __restrict__ x_bf,
                                              const float* __restrict__ ws_s,
                                              const float* __restrict__ ws_d,
                                              float* __restrict__ a_s,
                                              float* __restrict__ a_d)
{
    int wid = threadIdx.x >> 6, lane = threadIdx.x & 63;
    int n = blockIdx.x * 4 + wid;
    ushort4 xv = *(const ushort4*)(x_bf + (size_t)n * HDIM + lane * 4);
    float x0 = b2f(xv.x), x1 = b2f(xv.y), x2 = b2f(xv.z), x3 = b2f(xv.w);
    float ss[4], sd[4];
    #pragma unroll
    for (int h = 0; h < 4; h++) {
        float4 s4 = *(const float4*)(ws_s + h * HDIM + lane * 4);
        float4 d4 = *(const float4*)(ws_d + h * HDIM + lane * 4);
        ss[h] = x0 * s4.x + x1 * s4.y + x2 * s4.z + x3 * s4.w;
        sd[h] = x0 * d4.x + x1 * d4.y + x2 * d4.z + x3 * d4.w;
    }
    #pragma unroll
    for (int off = 32; off > 0; off >>= 1)
        #pragma unroll
        for (int h = 0; h < 4; h++) {
            ss[h] += __shfl_xor(ss[h], off, 64);
            sd[h] += __shfl_xor(sd[h], off, 64);
        }
    if (lane == 0) {
        *(float4*)(a_s + n * 4) = make_float4(ss[0], ss[1], ss[2], ss[3]);
        *(float4*)(a_d + n * 4) = make_float4(sd[0], sd[1], sd[2], sd[3]);
    }
}

// z[pos][h] = leaky_relu(a_s[src] + a_d[dst] + c[h]*ew), CSR order, coalesced
__global__ __launch_bounds__(256) void edge_logits(const int* __restrict__ srcCSR,
                                                   const int* __restrict__ dstCSR,
                                                   const float* __restrict__ ewCSR4,
                                                   int l,
                                                   const float* __restrict__ a_s,
                                                   const float* __restrict__ a_d,
                                                   const float* __restrict__ scal,
                                                   float* __restrict__ zCSR)
{
    int pos = blockIdx.x * 256 + threadIdx.x;
    if (pos >= N_EDGES) return;
    int sn = srcCSR[pos], dn = dstCSR[pos];
    float4 wv = *(const float4*)(ewCSR4 + (size_t)pos * 4);
    float w = (l == 0) ? wv.x : (l == 1) ? wv.y : wv.z;
    float4 c4 = *(const float4*)scal;
    float4 zs = *(const float4*)(a_s + sn * 4);
    float4 zd = *(const float4*)(a_d + dn * 4);
    float4 z;
    z.x = zs.x + zd.x + c4.x * w; z.x = z.x > 0.f ? z.x : 0.2f * z.x;
    z.y = zs.y + zd.y + c4.y * w; z.y = z.y > 0.f ? z.y : 0.2f * z.y;
    z.z = zs.z + zd.z + c4.z * w; z.z = z.z > 0.f ? z.z : 0.2f * z.z;
    z.w = zs.w + zd.w + c4.w * w; z.w = z.w > 0.f ? z.w : 0.2f * z.w;
    ((float4*)zCSR)[pos] = z;
}

// Wave-per-node softmax + aggregate. 4 nodes/block, no __syncthreads.
__global__ __launch_bounds__(256) void gat_agg_wave(
    const unsigned short* __restrict__ x_bf, const float* __restrict__ a_s,
    const float* __restrict__ a_d, const float* __restrict__ loopw,
    const float* __restrict__ scal, const int* __restrict__ row_ptr,
    const int* __restrict__ srcCSR, const float* __restrict__ zCSR,
    unsigned short* __restrict__ agg)
{
    int wid = threadIdx.x >> 6, lane = threadIdx.x & 63;
    int n = blockIdx.x * 4 + wid;
    int r0 = row_ptr[n];
    int deg = row_ptr[n + 1] - r0;
    int cnt = deg + 1;

    float4 c4 = *(const float4*)scal;
    float4 as = *(const float4*)(a_s + n * 4);
    float4 ad = *(const float4*)(a_d + n * 4);
    float lw = loopw[n];
    float4 zself;
    zself.x = as.x + ad.x + c4.x * lw; zself.x = zself.x > 0.f ? zself.x : 0.2f * zself.x;
    zself.y = as.y + ad.y + c4.y * lw; zself.y = zself.y > 0.f ? zself.y : 0.2f * zself.y;
    zself.z = as.z + ad.z + c4.z * lw; zself.z = zself.z > 0.f ? zself.z : 0.2f * zself.z;
    zself.w = as.w + ad.w + c4.w * lw; zself.w = zself.w > 0.f ? zself.w : 0.2f * zself.w;

    auto load_z = [&](int c0) -> float4 {
        int idx = c0 + lane;
        if (idx < deg) return ((const float4*)zCSR)[r0 + idx];
        if (idx == deg) return zself;
        return make_float4(-1e30f, -1e30f, -1e30f, -1e30f);
    };
    auto load_s = [&](int c0) -> int {
        int idx = c0 + lane;
        return (idx < deg) ? srcCSR[r0 + idx] : n;
    };

    float4 zc0 = load_z(0);
    int sv0 = load_s(0);

    // stats pass 1: max
    float m0 = zc0.x, m1 = zc0.y, m2 = zc0.z, m3 = zc0.w;
    for (int c0 = 64; c0 < cnt; c0 += 64) {
        float4 z = load_z(c0);
        m0 = fmaxf(m0, z.x); m1 = fmaxf(m1, z.y);
        m2 = fmaxf(m2, z.z); m3 = fmaxf(m3, z.w);
    }
    #pragma unroll
    for (int off = 32; off > 0; off >>= 1) {
        m0 = fmaxf(m0, __shfl_xor(m0, off, 64));
        m1 = fmaxf(m1, __shfl_xor(m1, off, 64));
        m2 = fmaxf(m2, __shfl_xor(m2, off, 64));
        m3 = fmaxf(m3, __shfl_xor(m3, off, 64));
    }
    // stats pass 2: sum exp
    float s0 = __expf(zc0.x - m0), s1 = __expf(zc0.y - m1);
    float s2 = __expf(zc0.z - m2), s3 = __expf(zc0.w - m3);
    for (int c0 = 64; c0 < cnt; c0 += 64) {
        float4 z = load_z(c0);
        s0 += __expf(z.x - m0); s1 += __expf(z.y - m1);
        s2 += __expf(z.z - m2); s3 += __expf(z.w - m3);
    }
    #pragma unroll
    for (int off = 32; off > 0; off >>= 1) {
        s0 += __shfl_xor(s0, off, 64);
        s1 += __shfl_xor(s1, off, 64);
        s2 += __shfl_xor(s2, off, 64);
        s3 += __shfl_xor(s3, off, 64);
    }
    float i0 = 1.f / s0, i1 = 1.f / s1, i2 = 1.f / s2, i3 = 1.f / s3;

    // aggregation
    float acc[4][4] = {};
    const unsigned short* xw = x_bf + (size_t)lane * 4;
    for (int c0 = 0; c0 < cnt; c0 += 64) {
        float4 z = (c0 == 0) ? zc0 : load_z(c0);
        int sv = (c0 == 0) ? sv0 : load_s(c0);
        int mc = min(64, cnt - c0);
        int j = 0;
        for (; j + 1 < mc; j += 2) {
            int sA = __builtin_amdgcn_readfirstlane(__shfl(sv, j, 64));
            int sB = __builtin_amdgcn_readfirstlane(__shfl(sv, j + 1, 64));
            uint2 uA = *(const uint2*)(xw + (size_t)sA * HDIM);
            uint2 uB = *(const uint2*)(xw + (size_t)sB * HDIM);
            float aA0 = __expf(__shfl(z.x, j, 64) - m0) * i0;
            float aA1 = __expf(__shfl(z.y, j, 64) - m1) * i1;
            float aA2 = __expf(__shfl(z.z, j, 64) - m2) * i2;
            float aA3 = __expf(__shfl(z.w, j, 64) - m3) * i3;
            float aB0 = __expf(__shfl(z.x, j + 1, 64) - m0) * i0;
            float aB1 = __expf(__shfl(z.y, j + 1, 64) - m1) * i1;
            float aB2 = __expf(__shfl(z.z, j + 1, 64) - m2) * i2;
            float aB3 = __expf(__shfl(z.w, j + 1, 64) - m3) * i3;
            float xa0 = b2f_lo(uA.x), xa1 = b2f_hi(uA.x), xa2 = b2f_lo(uA.y), xa3 = b2f_hi(uA.y);
            float xb0 = b2f_lo(uB.x), xb1 = b2f_hi(uB.x), xb2 = b2f_lo(uB.y), xb3 = b2f_hi(uB.y);
            acc[0][0] += aA0 * xa0 + aB0 * xb0; acc[0][1] += aA0 * xa1 + aB0 * xb1;
            acc[0][2] += aA0 * xa2 + aB0 * xb2; acc[0][3] += aA0 * xa3 + aB0 * xb3;
            acc[1][0] += aA1 * xa0 + aB1 * xb0; acc[1][1] += aA1 * xa1 + aB1 * xb1;
            acc[1][2] += aA1 * xa2 + aB1 * xb2; acc[1][3] += aA1 * xa3 + aB1 * xb3;
            acc[2][0] += aA2 * xa0 + aB2 * xb0; acc[2][1] += aA2 * xa1 + aB2 * xb1;
            acc[2][2] += aA2 * xa2 + aB2 * xb2; acc[2][3] += aA2 * xa3 + aB2 * xb3;
            acc[3][0] += aA3 * xa0 + aB3 * xb0; acc[3][1] += aA3 * xa1 + aB3 * xb1;
            acc[3][2] += aA3 * xa2 + aB3 * xb2; acc[3][3] += aA3 * xa3 + aB3 * xb3;
        }
        if (j < mc) {
            int sA = __builtin_amdgcn_readfirstlane(__shfl(sv, j, 64));
            uint2 uA = *(const uint2*)(xw + (size_t)sA * HDIM);
            float aA0 = __expf(__shfl(z.x, j, 64) - m0) * i0;
            float aA1 = __expf(__shfl(z.y, j, 64) - m1) * i1;
            float aA2 = __expf(__shfl(z.z, j, 64) - m2) * i2;
            float aA3 = __expf(__shfl(z.w, j, 64) - m3) * i3;
            float xa0 = b2f_lo(uA.x), xa1 = b2f_hi(uA.x), xa2 = b2f_lo(uA.y), xa3 = b2f_hi(uA.y);
            acc[0][0] += aA0 * xa0; acc[0][1] += aA0 * xa1; acc[0][2] += aA0 * xa2; acc[0][3] += aA0 * xa3;
            acc[1][0] += aA1 * xa0; acc[1][1] += aA1 * xa1; acc[1][2] += aA1 * xa2; acc[1][3] += aA1 * xa3;
            acc[2][0] += aA2 * xa0; acc[2][1] += aA2 * xa1; acc[2][2] += aA2 * xa2; acc[2][3] += aA2 * xa3;
            acc[3][0] += aA3 * xa0; acc[3][1] += aA3 * xa1; acc[3][2] += aA3 * xa2; acc[3][3] += aA3 * xa3;
        }
    }

    unsigned short* ag = agg + (size_t)n * NH + lane * 4;
    #pragma unroll
    for (int h = 0; h < 4; h++) {
        ushort4 o;
        o.x = f2b(acc[h][0]); o.y = f2b(acc[h][1]);
        o.z = f2b(acc[h][2]); o.w = f2b(acc[h][3]);
        *(ushort4*)(ag + h * 256) = o;
    }
}

// LN(y) + residual ReLU, in-place x. One wave per node.
__global__ __launch_bounds__(256) void ln_residual(const unsigned short* __restrict__ y_bf,
                                                   const float* __restrict__ ln_g,
                                                   const float* __restrict__ ln_b,
                                                   unsigned short* __restrict__ x_bf)
{
    int n = blockIdx.x * 4 + (threadIdx.x >> 6);
    int lane = threadIdx.x & 63;
    ushort4 yv = *(const ushort4*)(y_bf + (size_t)n * HDIM + lane * 4);
    float y0 = b2f(yv.x), y1 = b2f(yv.y), y2 = b2f(yv.z), y3 = b2f(yv.w);
    float s1 = y0 + y1 + y2 + y3;
    float s2 = y0 * y0 + y1 * y1 + y2 * y2 + y3 * y3;
    #pragma unroll
    for (int off = 32; off > 0; off >>= 1) {
        s1 += __shfl_xor(s1, off, 64);
        s2 += __shfl_xor(s2, off, 64);
    }
    float mu = s1 * (1.f / HDIM);
    float var = s2 * (1.f / HDIM) - mu * mu;
    float rsig = rsqrtf(var + 1e-5f);
    float4 g = *(const float4*)(ln_g + lane * 4);
    float4 b = *(const float4*)(ln_b + lane * 4);
    ushort4 xv = *(const ushort4*)(x_bf + (size_t)n * HDIM + lane * 4);
    ushort4 o;
    o.x = f2b(fmaxf(b2f(xv.x) + g.x * (y0 - mu) * rsig + b.x, 0.f));
    o.y = f2b(fmaxf(b2f(xv.y) + g.y * (y1 - mu) * rsig + b.y, 0.f));
    o.z = f2b(fmaxf(b2f(xv.z) + g.z * (y2 - mu) * rsig + b.z, 0.f));
    o.w = f2b(fmaxf(b2f(xv.w) + g.w * (y3 - mu) * rsig + b.w, 0.f));
    *(ushort4*)(x_bf + (size_t)n * HDIM + lane * 4) = o;
}

__global__ __launch_bounds__(256) void head2_kernel(const unsigned short* __restrict__ hmid,
                                                    const float* __restrict__ w2,
                                                    const float* __restrict__ b2,
                                                    float* __restrict__ out)
{
    int gw = blockIdx.x * 4 + (threadIdx.x >> 6);
    int lane = threadIdx.x & 63;
    int n = gw >> 2;
    int k = gw & 3;
    const unsigned short* hr = hmid + (size_t)n * 512 + k * 128;
    const float* wr = w2 + k * 128;
    float s = b2f(hr[lane]) * wr[lane] + b2f(hr[lane + 64]) * wr[lane + 64];
    s = wave_reduce_sum(s);
    if (lane == 0) {
        s += b2[k];
        if (k == 0 || k == 3) s = 1.f / (1.f + __expf(-s));
        out[(size_t)k * N_NODES + n] = s;
    }
}

__global__ void copy_emb(const unsigned short* __restrict__ x_bf, float* __restrict__ out) {
    int i = blockIdx.x * 256 + threadIdx.x;
    ushort4 v = ((const ushort4*)x_bf)[i];
    float4 o = make_float4(b2f(v.x), b2f(v.y), b2f(v.z), b2f(v.w));
    ((float4*)out)[i] = o;
}

extern "C" void kernel_launch(void* const* d_in, const int* in_sizes, int n_in,
                              void* d_out, int out_size, void* d_ws, size_t ws_size,
                              hipStream_t stream) {
    const float* node_features = (const float*)d_in[0];
    const float* edge_attr     = (const float*)d_in[1];
    const float* enc_w         = (const float*)d_in[2];
    const float* enc_b         = (const float*)d_in[3];
    const float* edge_enc_w    = (const float*)d_in[4];
    const float* edge_enc_b    = (const float*)d_in[5];
    const float* gat_w         = (const float*)d_in[6];
    const float* att_src       = (const float*)d_in[7];
    const float* att_dst       = (const float*)d_in[8];
    const float* att_edge      = (const float*)d_in[9];
    const float* lin_edge_w    = (const float*)d_in[10];
    const float* gat_b         = (const float*)d_in[11];
    const float* ln_g          = (const float*)d_in[12];
    const float* ln_b          = (const float*)d_in[13];
    const float* head_w1       = (const float*)d_in[14];
    const float* head_b1       = (const float*)d_in[15];
    const float* head_w2       = (const float*)d_in[16];
    const float* head_b2       = (const float*)d_in[17];
    const int*   edge_index    = (const int*)d_in[18];
    const int* src0 = edge_index;
    const int* dst0 = edge_index + N_EDGES;
    float* out = (float*)d_out;

    char* cur = (char*)d_ws;
    auto alloc = [&](size_t bytes) { char* p = cur; cur += (bytes + 255) & ~(size_t)255; return p; };
    unsigned short* x_bf   = (unsigned short*)alloc((size_t)N_NODES * HDIM * 2);
    unsigned short* agg    = (unsigned short*)alloc((size_t)N_NODES * NH * 2);   // also hmid
    unsigned short* y_bf   = (unsigned short*)alloc((size_t)N_NODES * HDIM * 2);
    unsigned short* nf_bf  = (unsigned short*)alloc((size_t)N_NODES * NDIM * 2);
    unsigned short* enc_wt = (unsigned short*)alloc((size_t)HDIM * NDIM * 2);
    unsigned short* gw2t   = (unsigned short*)alloc((size_t)NLAYERS * NH * HDIM * 2);
    unsigned short* hw1t   = (unsigned short*)alloc((size_t)512 * HDIM * 2);
    float* ws_s   = (float*)alloc((size_t)NLAYERS * 4 * HDIM * 4);
    float* ws_d   = (float*)alloc((size_t)NLAYERS * 4 * HDIM * 4);
    float* a_s    = (float*)alloc((size_t)N_NODES * 4 * 4);
    float* a_d    = (float*)alloc((size_t)N_NODES * 4 * 4);
    float* ewCSR4 = (float*)alloc((size_t)N_EDGES * 4 * 4);
    float* loopw3 = (float*)alloc((size_t)3 * N_NODES * 4);
    float* zCSR   = (float*)alloc((size_t)N_EDGES * 4 * 4);
    float* wmean3 = (float*)alloc(192 * 4);
    float* scal3  = (float*)alloc(24 * 4);
    // cnt+fillc contiguous: single memset must cover both exactly (R2 lesson)
    int* cnt      = (int*)alloc((size_t)2 * N_NODES * 4);
    int* fillc    = cnt + N_NODES;
    int* row_ptr  = (int*)alloc((size_t)(N_NODES + 1) * 4);
    int* bsum     = (int*)alloc((size_t)(SCAN_NBLK + 1) * 4);
    int* boff     = (int*)alloc((size_t)(SCAN_NBLK + 1) * 4);
    int* srcCSR   = (int*)alloc((size_t)N_EDGES * 4);
    int* dstCSR   = (int*)alloc((size_t)N_EDGES * 4);
    int* pose     = (int*)alloc((size_t)N_EDGES * 4);
    unsigned short* hmid = agg;

    hipMemsetAsync(cnt, 0, (size_t)2 * N_NODES * sizeof(int), stream);

    hist_kernel<<<(N_EDGES + 255) / 256, 256, 0, stream>>>(dst0, cnt);
    scan_local<<<SCAN_NBLK, 256, 0, stream>>>(cnt, row_ptr, bsum);
    scan_bsums<<<1, 128, 0, stream>>>(bsum, boff);
    scan_add<<<SCAN_NBLK, 256, 0, stream>>>(row_ptr, boff);
    fill_kernel<<<(N_EDGES + 255) / 256, 256, 0, stream>>>(src0, dst0, row_ptr, fillc,
                                                           srcCSR, dstCSR, pose);

    conv_bf<<<(N_NODES * NDIM / 4) / 256, 256, 0, stream>>>(node_features, nf_bf);
    transpose_bf<<<dim3(HDIM / 32, NDIM / 32, 1), dim3(32, 8), 0, stream>>>(
        enc_w, enc_wt, NDIM, HDIM, 0, 0);
    gat_w_prep<<<dim3(8, 8, 12), dim3(32, 8), 0, stream>>>(gat_w, gw2t);
    ws_prep<<<12, 256, 0, stream>>>(gat_w, att_src, att_dst, ws_s, ws_d);
    transpose_bf<<<dim3(128 / 32, HDIM / 32, 4), dim3(32, 8), 0, stream>>>(
        head_w1, hw1t, HDIM, 128, (size_t)HDIM * 128, (size_t)128 * HDIM);

    layer_prep3<<<3, 128, 0, stream>>>(edge_enc_w, edge_enc_b, lin_edge_w, att_edge, wmean3, scal3);
    edge_weights_all<<<(N_EDGES + 255) / 256, 256, 0, stream>>>(edge_attr, wmean3, scal3,
                                                                pose, ewCSR4);
    loop_weights_all<<<(N_NODES + 255) / 256, 256, 0, stream>>>(ewCSR4, row_ptr, loopw3);

    gemm_bf16<true, true><<<dim3(HDIM / 128, (N_NODES + 127) / 128), 256, 0, stream>>>(
        nf_bf, enc_wt, enc_b, x_bf, N_NODES, HDIM, NDIM);

    for (int l = 0; l < NLAYERS; l++) {
        attn_x<<<N_NODES / 4, 256, 0, stream>>>(x_bf, ws_s + (size_t)l * 4 * HDIM,
                                                ws_d + (size_t)l * 4 * HDIM, a_s, a_d);
        edge_logits<<<(N_EDGES + 255) / 256, 256, 0, stream>>>(
            srcCSR, dstCSR, ewCSR4, l, a_s, a_d, scal3 + l * 8, zCSR);
        gat_agg_wave<<<N_NODES / 4, 256, 0, stream>>>(
            x_bf, a_s, a_d, loopw3 + (size_t)l * N_NODES, scal3 + l * 8,
            row_ptr, srcCSR, zCSR, agg);
        gemm_bf16<false, true><<<dim3(HDIM / 128, (N_NODES + 127) / 128), 256, 0, stream>>>(
            agg, gw2t + (size_t)l * NH * HDIM, gat_b + (size_t)l * HDIM, y_bf,
            N_NODES, HDIM, NH);
        ln_residual<<<N_NODES / 4, 256, 0, stream>>>(y_bf, ln_g + (size_t)l * HDIM,
                                                     ln_b + (size_t)l * HDIM, x_bf);
    }

    gemm_bf16<true, true><<<dim3(512 / 128, (N_NODES + 127) / 128), 256, 0, stream>>>(
        x_bf, hw1t, head_b1, hmid, N_NODES, 512, HDIM);
    head2_kernel<<<N_NODES, 256, 0, stream>>>(hmid, head_w2, head_b2, out);

    copy_emb<<<(N_NODES * HDIM / 4) / 256, 256, 0, stream>>>(x_bf, out + 4 * N_NODES);
}